// Round 9
// baseline (1800.971 us; speedup 1.0000x reference)
//
#include <hip/hip_runtime.h>
#include <math.h>

#define BT 4096
#define CDIM 768
#define NHEAD 12
#define DH 64
#define TSEQ 1024
#define BBATCH 4

typedef _Float16 f16;
typedef __attribute__((ext_vector_type(4))) _Float16 f16x4;
typedef __attribute__((ext_vector_type(8))) _Float16 f16x8;
typedef __attribute__((ext_vector_type(4))) float f32x4;

__device__ __forceinline__ void gload_lds16(const f16* g, f16* l) {
  __builtin_amdgcn_global_load_lds(
      (const __attribute__((address_space(1))) unsigned*)(const void*)g,
      (__attribute__((address_space(3))) unsigned*)(void*)l, 16, 0, 0);
}

// ---------------- block reduction (256 threads = 4 waves) ----------------
__device__ __forceinline__ float block_reduce_sum(float v, float* sbuf) {
#pragma unroll
  for (int o = 32; o > 0; o >>= 1) v += __shfl_down(v, o, 64);
  int lane = threadIdx.x & 63;
  int w = threadIdx.x >> 6;
  if (lane == 0) sbuf[w] = v;
  __syncthreads();
  float r = sbuf[0] + sbuf[1] + sbuf[2] + sbuf[3];
  __syncthreads();
  return r;
}

// ---------------- zero-fill ----------------------------------------------
__global__ __launch_bounds__(256) void zero_kernel(float4* __restrict__ p) {
  p[(size_t)blockIdx.x * 256 + threadIdx.x] = make_float4(0.f, 0.f, 0.f, 0.f);
}

// ---------------- fp32 -> fp16 weight conversion (4 elems/thread) --------
__global__ __launch_bounds__(256) void cvt_f16_kernel(
    const float* __restrict__ in, f16* __restrict__ out) {
  size_t i = ((size_t)blockIdx.x * 256 + threadIdx.x) * 4;
  float4 v = *(const float4*)(in + i);
  f16x4 o = {(f16)v.x, (f16)v.y, (f16)v.z, (f16)v.w};
  *(f16x4*)(out + i) = o;
}

// ---------------- LN1: x_h = f16(LN(z + 0.1*emb + u) * w + b) ------------
__global__ __launch_bounds__(256) void ln1_kernel(
    const float* __restrict__ z, const float* __restrict__ u,
    const float* __restrict__ emb, const float* __restrict__ w,
    const float* __restrict__ b, f16* __restrict__ x) {
  __shared__ float sbuf[4];
  int row = blockIdx.x;
  int tid = threadIdx.x;
  const float* zr = z + (size_t)row * CDIM;
  const float* ur = u + (size_t)row * CDIM;
  float v[3];
  float s = 0.f;
#pragma unroll
  for (int i = 0; i < 3; i++) {
    int c = tid + i * 256;
    v[i] = zr[c] + 0.1f * emb[c] + ur[c];
    s += v[i];
  }
  s = block_reduce_sum(s, sbuf);
  float mu = s * (1.f / CDIM);
  float sq = 0.f;
#pragma unroll
  for (int i = 0; i < 3; i++) { v[i] -= mu; sq += v[i] * v[i]; }
  sq = block_reduce_sum(sq, sbuf);
  float rstd = rsqrtf(sq * (1.f / CDIM) + 1e-5f);
  f16* xr = x + (size_t)row * CDIM;
#pragma unroll
  for (int i = 0; i < 3; i++) {
    int c = tid + i * 256;
    xr[c] = (f16)(v[i] * rstd * w[c] + b[c]);
  }
}

// ---------------- LN2 ----------------------------------------------------
__global__ __launch_bounds__(256) void ln2_kernel(
    const float* __restrict__ in, const float* __restrict__ w,
    const float* __restrict__ b, f16* __restrict__ x) {
  __shared__ float sbuf[4];
  int row = blockIdx.x;
  int tid = threadIdx.x;
  const float* ir = in + (size_t)row * CDIM;
  float v[3];
  float s = 0.f;
#pragma unroll
  for (int i = 0; i < 3; i++) {
    int c = tid + i * 256;
    v[i] = ir[c];
    s += v[i];
  }
  s = block_reduce_sum(s, sbuf);
  float mu = s * (1.f / CDIM);
  float sq = 0.f;
#pragma unroll
  for (int i = 0; i < 3; i++) { v[i] -= mu; sq += v[i] * v[i]; }
  sq = block_reduce_sum(sq, sbuf);
  float rstd = rsqrtf(sq * (1.f / CDIM) + 1e-5f);
  f16* xr = x + (size_t)row * CDIM;
#pragma unroll
  for (int i = 0; i < 3; i++) {
    int c = tid + i * 256;
    xr[c] = (f16)(v[i] * rstd * w[c] + b[c]);
  }
}

__device__ __forceinline__ float gelu_exact(float t) {
  return 0.5f * t * (1.f + erff(t * 0.70710678118654752f));
}

// ---------------- fp16 MFMA GEMM 128x128 (m97 structure) -----------------
// MODE 1 only now: hout = f16(gelu(acc + bias))   (mlp1, 768 blocks = 3/CU)
template <int MODE>
__global__ __launch_bounds__(256) void gemm_mfma(
    const f16* __restrict__ A, const f16* __restrict__ W,
    const float* __restrict__ bias, f16* __restrict__ hout,
    int M, int N, int K) {
  __shared__ __align__(16) f16 As[128 * 32];
  __shared__ __align__(16) f16 Bs[128 * 32];
  int tid = threadIdx.x;
  int wv = tid >> 6, lane = tid & 63;
  int bm = blockIdx.y, bn = blockIdx.x;
  int wm = (wv >> 1) * 64, wn = (wv & 1) * 64;

  int srow = wv * 16 + (lane >> 2);
  int scol = (lane & 3) * 8;
  const f16* gA = A + (size_t)(bm * 128 + srow) * K + scol;
  const f16* gB = W + (size_t)(bn * 128 + srow) * K + scol;
  f16* lA = As + wv * 16 * 32;
  f16* lB = Bs + wv * 16 * 32;

  f32x4 acc[4][4];
#pragma unroll
  for (int i = 0; i < 4; i++)
#pragma unroll
    for (int j = 0; j < 4; j++) acc[i][j] = (f32x4){0.f, 0.f, 0.f, 0.f};

  int arow = lane & 15;
  int koff = (lane >> 4) * 8;

  for (int k0 = 0; k0 < K; k0 += 32) {
    __syncthreads();
    gload_lds16(gA + k0, lA);
    gload_lds16(gA + (size_t)64 * K + k0, lA + 64 * 32);
    gload_lds16(gB + k0, lB);
    gload_lds16(gB + (size_t)64 * K + k0, lB + 64 * 32);
    __syncthreads();
    f16x8 af[4], bfr[4];
#pragma unroll
    for (int mi = 0; mi < 4; mi++)
      af[mi] = *(const f16x8*)&As[(wm + mi * 16 + arow) * 32 + koff];
#pragma unroll
    for (int nj = 0; nj < 4; nj++)
      bfr[nj] = *(const f16x8*)&Bs[(wn + nj * 16 + arow) * 32 + koff];
#pragma unroll
    for (int mi = 0; mi < 4; mi++)
#pragma unroll
      for (int nj = 0; nj < 4; nj++)
        acc[mi][nj] = __builtin_amdgcn_mfma_f32_16x16x32_f16(
            af[mi], bfr[nj], acc[mi][nj], 0, 0, 0);
  }

  int crow0 = bm * 128 + wm + (lane >> 4) * 4;
  int ccol0 = bn * 128 + wn + (lane & 15);
#pragma unroll
  for (int nj = 0; nj < 4; nj++) {
    int col = ccol0 + nj * 16;
    float bcol = bias[col];
#pragma unroll
    for (int mi = 0; mi < 4; mi++) {
#pragma unroll
      for (int r = 0; r < 4; r++) {
        int m = crow0 + mi * 16 + r;
        size_t idx = (size_t)m * N + col;
        hout[idx] = (f16)gelu_exact(acc[mi][nj][r] + bcol);
      }
    }
  }
}

// ---------------- qkv GEMM: 64x128 tile (occupancy: 1152 blocks = 4.5/CU) -
// A [M,768] f16, W [2304,768] f16. 4 waves split N (32 cols each, all 64
// rows): 4x2 MFMAs/wave. Scatter epilogue: q/k [B,H,T,64], v^T [B,H,64,T].
// N-tiles never straddle the q/k/v boundary (128 | 768).
__global__ __launch_bounds__(256) void gemm_qkv(
    const f16* __restrict__ A, const f16* __restrict__ W,
    const float* __restrict__ bias, f16* __restrict__ hq,
    f16* __restrict__ hk, f16* __restrict__ hvt, int K) {
  __shared__ __align__(16) f16 As[64 * 32];
  __shared__ __align__(16) f16 Bs[128 * 32];
  int tid = threadIdx.x;
  int wv = tid >> 6, lane = tid & 63;
  int bm = blockIdx.y, bn = blockIdx.x;

  int srow = wv * 16 + (lane >> 2);
  int scol = (lane & 3) * 8;
  const f16* gA = A + (size_t)(bm * 64 + srow) * K + scol;
  const f16* gB = W + (size_t)(bn * 128 + srow) * K + scol;
  f16* lA = As + wv * 16 * 32;
  f16* lB = Bs + wv * 16 * 32;

  f32x4 acc[4][2];
#pragma unroll
  for (int i = 0; i < 4; i++)
#pragma unroll
    for (int j = 0; j < 2; j++) acc[i][j] = (f32x4){0.f, 0.f, 0.f, 0.f};

  int arow = lane & 15;
  int koff = (lane >> 4) * 8;

  for (int k0 = 0; k0 < K; k0 += 32) {
    __syncthreads();
    gload_lds16(gA + k0, lA);
    gload_lds16(gB + k0, lB);
    gload_lds16(gB + (size_t)64 * K + k0, lB + 64 * 32);
    __syncthreads();
    f16x8 af[4], bfr[2];
#pragma unroll
    for (int mi = 0; mi < 4; mi++)
      af[mi] = *(const f16x8*)&As[(mi * 16 + arow) * 32 + koff];
#pragma unroll
    for (int nj = 0; nj < 2; nj++)
      bfr[nj] = *(const f16x8*)&Bs[(wv * 32 + nj * 16 + arow) * 32 + koff];
#pragma unroll
    for (int mi = 0; mi < 4; mi++)
#pragma unroll
      for (int nj = 0; nj < 2; nj++)
        acc[mi][nj] = __builtin_amdgcn_mfma_f32_16x16x32_f16(
            af[mi], bfr[nj], acc[mi][nj], 0, 0, 0);
  }

  int crow0 = bm * 64 + (lane >> 4) * 4;
  int ccol0 = bn * 128 + wv * 32 + (lane & 15);
#pragma unroll
  for (int nj = 0; nj < 2; nj++) {
    int col = ccol0 + nj * 16;
    float bcol = bias[col];
    int which = col / CDIM;
    int rem = col - which * CDIM;
    int h = rem >> 6;
    int d = rem & 63;
#pragma unroll
    for (int mi = 0; mi < 4; mi++) {
#pragma unroll
      for (int r = 0; r < 4; r++) {
        int m = crow0 + mi * 16 + r;
        int bb = m >> 10, t = m & 1023;
        f16 val = (f16)(acc[mi][nj][r] + bcol);
        if (which == 0)
          hq[(((size_t)(bb * NHEAD + h) * TSEQ + t) << 6) + d] = val;
        else if (which == 1)
          hk[(((size_t)(bb * NHEAD + h) * TSEQ + t) << 6) + d] = val;
        else
          hvt[(((size_t)(bb * NHEAD + h) * DH + d) << 10) + t] = val;
      }
    }
  }
}

// ---------------- fp16 MFMA GEMM 64x64 (occupancy variant, N=768 GEMMs) --
// MODE 0: fout0 = acc + bias + aux1               (out-proj residual)
// MODE 2: fout0 = acc + bias + aux1 - aux2        (mlp2 -> residual F)
template <int MODE>
__global__ __launch_bounds__(256) void gemm_mfma64(
    const f16* __restrict__ A, const f16* __restrict__ W,
    const float* __restrict__ bias, const float* __restrict__ aux1,
    const float* __restrict__ aux2, float* __restrict__ fout0,
    int M, int N, int K) {
  __shared__ __align__(16) f16 As[64 * 32];
  __shared__ __align__(16) f16 Bs[64 * 32];
  int tid = threadIdx.x;
  int wv = tid >> 6, lane = tid & 63;
  int bm = blockIdx.y, bn = blockIdx.x;
  int wm = (wv >> 1) * 32, wn = (wv & 1) * 32;

  int srow = wv * 16 + (lane >> 2);
  int scol = (lane & 3) * 8;
  const f16* gA = A + (size_t)(bm * 64 + srow) * K + scol;
  const f16* gB = W + (size_t)(bn * 64 + srow) * K + scol;
  f16* lA = As + wv * 16 * 32;
  f16* lB = Bs + wv * 16 * 32;

  f32x4 acc[2][2];
#pragma unroll
  for (int i = 0; i < 2; i++)
#pragma unroll
    for (int j = 0; j < 2; j++) acc[i][j] = (f32x4){0.f, 0.f, 0.f, 0.f};

  int arow = lane & 15;
  int koff = (lane >> 4) * 8;

  for (int k0 = 0; k0 < K; k0 += 32) {
    __syncthreads();
    gload_lds16(gA + k0, lA);
    gload_lds16(gB + k0, lB);
    __syncthreads();
    f16x8 af[2], bfr[2];
#pragma unroll
    for (int mi = 0; mi < 2; mi++)
      af[mi] = *(const f16x8*)&As[(wm + mi * 16 + arow) * 32 + koff];
#pragma unroll
    for (int nj = 0; nj < 2; nj++)
      bfr[nj] = *(const f16x8*)&Bs[(wn + nj * 16 + arow) * 32 + koff];
#pragma unroll
    for (int mi = 0; mi < 2; mi++)
#pragma unroll
      for (int nj = 0; nj < 2; nj++)
        acc[mi][nj] = __builtin_amdgcn_mfma_f32_16x16x32_f16(
            af[mi], bfr[nj], acc[mi][nj], 0, 0, 0);
  }

  int crow0 = bm * 64 + wm + (lane >> 4) * 4;
  int ccol0 = bn * 64 + wn + (lane & 15);
#pragma unroll
  for (int nj = 0; nj < 2; nj++) {
    int col = ccol0 + nj * 16;
    float bcol = bias[col];
#pragma unroll
    for (int mi = 0; mi < 2; mi++) {
#pragma unroll
      for (int r = 0; r < 4; r++) {
        int m = crow0 + mi * 16 + r;
        size_t idx = (size_t)m * N + col;
        float val = acc[mi][nj][r] + bcol;
        if constexpr (MODE == 0) {
          fout0[idx] = val + aux1[idx];
        } else {  // MODE 2
          fout0[idx] = val + aux1[idx] - aux2[idx];
        }
      }
    }
  }
}

// ---------------- MFMA flash attention v6: pipelined, XCD-swizzled -------
// R7 base (256 thr, fixed-shift softmax). Changes:
//  * grid (48 bh, 16 qchunk): the 16 blocks sharing one (b,h)'s K/V have
//    linear IDs spaced 48 (== 0 mod 8) apart -> same XCD -> L2 reuse.
//  * K fragments double-buffered (prefetch n0+64 at loop top); V fragments
//    issued before the exp/P phase -> global latency off the critical path.
//  * no asm waitcnt/memory clobber: compiler's LDS alias analysis orders
//    the P write->read round-trip itself (m120-verified pattern) and no
//    longer pins V/K loads behind the DS drain.
#define PSTRIDE 72
__global__ __launch_bounds__(256) void flash_attn6(
    const f16* __restrict__ Qg, const f16* __restrict__ Kg,
    const f16* __restrict__ Vt, f16* __restrict__ attn) {
  __shared__ __align__(16) f16 Plds[4][16 * PSTRIDE];
  int wv = threadIdx.x >> 6, lane = threadIdx.x & 63;
  int bh = blockIdx.x;  // swizzle: bh fastest
  int bb = bh / NHEAD, h = bh % NHEAD;
  int m0 = (blockIdx.y * 4 + wv) * 16;
  int am = lane & 15;
  int quad = lane >> 4;
  int ak = quad * 8;

  const f16* qbase = Qg + (((size_t)bh * TSEQ + m0) << 6);
  f16x8 qf0 = *(const f16x8*)(qbase + am * 64 + ak);
  f16x8 qf1 = *(const f16x8*)(qbase + am * 64 + 32 + ak);
#pragma unroll
  for (int i = 0; i < 8; i++) { qf0[i] *= (f16)0.125f; qf1[i] *= (f16)0.125f; }

  const f16* kb = Kg + (((size_t)bh * TSEQ) << 6);
  const f16* vb = Vt + (((size_t)bh * DH) << 10);
  f16* Pw = Plds[wv];

  f32x4 Oa[4];
#pragma unroll
  for (int i = 0; i < 4; i++) Oa[i] = (f32x4){0.f, 0.f, 0.f, 0.f};
  float lpart[4] = {0.f, 0.f, 0.f, 0.f};

  // prefetch K fragments for tile 0
  f16x8 kc0[4], kc1[4];
#pragma unroll
  for (int t = 0; t < 4; t++) {
    const f16* kr = kb + (((size_t)(16 * t + am)) << 6);
    kc0[t] = *(const f16x8*)(kr + ak);
    kc1[t] = *(const f16x8*)(kr + 32 + ak);
  }

  for (int n0 = 0; n0 < TSEQ; n0 += 64) {
    // issue next K tile loads first (in flight across this iteration)
    int nn = (n0 + 64) & (TSEQ - 1);  // last iter wraps to 0: harmless
    f16x8 kn0[4], kn1[4];
#pragma unroll
    for (int t = 0; t < 4; t++) {
      const f16* kr = kb + (((size_t)(nn + 16 * t + am)) << 6);
      kn0[t] = *(const f16x8*)(kr + ak);
      kn1[t] = *(const f16x8*)(kr + 32 + ak);
    }
    // ---- S = Q K^T from current (prefetched) K fragments ----
    f32x4 S[4];
#pragma unroll
    for (int t = 0; t < 4; t++) {
      S[t] = __builtin_amdgcn_mfma_f32_16x16x32_f16(
          qf0, kc0[t], (f32x4){0.f, 0.f, 0.f, 0.f}, 0, 0, 0);
      S[t] = __builtin_amdgcn_mfma_f32_16x16x32_f16(qf1, kc1[t], S[t], 0, 0, 0);
    }
    // issue V loads now — independent of exp/P, latency hidden behind them
    f16x8 vf0[4], vf1[4];
#pragma unroll
    for (int dt = 0; dt < 4; dt++) {
      const f16* vr = vb + (((size_t)(16 * dt + am)) << 10) + n0;
      vf0[dt] = *(const f16x8*)(vr + ak);
      vf1[dt] = *(const f16x8*)(vr + 32 + ak);
    }
    // ---- p = exp(s) (fixed shift), accumulate l, stage P to LDS ----
#pragma unroll
    for (int t = 0; t < 4; t++) {
#pragma unroll
      for (int r = 0; r < 4; r++) {
        float p = __expf(S[t][r]);
        lpart[r] += p;
        Pw[(quad * 4 + r) * PSTRIDE + 16 * t + am] = (f16)p;
      }
    }
    // ---- P (A-layout from LDS; compiler orders vs the writes) @ V ----
    f16x8 pa0 = *(const f16x8*)&Pw[am * PSTRIDE + ak];
    f16x8 pa1 = *(const f16x8*)&Pw[am * PSTRIDE + 32 + ak];
#pragma unroll
    for (int dt = 0; dt < 4; dt++) {
      Oa[dt] = __builtin_amdgcn_mfma_f32_16x16x32_f16(pa0, vf0[dt], Oa[dt], 0, 0, 0);
      Oa[dt] = __builtin_amdgcn_mfma_f32_16x16x32_f16(pa1, vf1[dt], Oa[dt], 0, 0, 0);
    }
    // rotate K double-buffer
#pragma unroll
    for (int t = 0; t < 4; t++) { kc0[t] = kn0[t]; kc1[t] = kn1[t]; }
  }

  // ---- single final l reduction across the 16 lanes of each quad-row ----
#pragma unroll
  for (int o = 1; o < 16; o <<= 1)
#pragma unroll
    for (int r = 0; r < 4; r++) lpart[r] += __shfl_xor(lpart[r], o, 64);

  // ---- epilogue: O[m][d] / l -> attn (f16 [B,T,C] at col h*64+d) ----
#pragma unroll
  for (int r = 0; r < 4; r++) {
    int m = m0 + quad * 4 + r;
    float inv = 1.f / lpart[r];
    f16* orow = attn + ((size_t)(bb * TSEQ + m)) * CDIM + h * DH;
#pragma unroll
    for (int dt = 0; dt < 4; dt++)
      orow[dt * 16 + am] = (f16)(Oa[dt][r] * inv);
  }
}

// ---------------- Anderson: first iteration (K=0): z += res --------------
__global__ __launch_bounds__(256) void add_res_kernel(
    float* __restrict__ z, const float* __restrict__ r) {
  size_t i = (size_t)blockIdx.x * 256 + threadIdx.x;
  z[i] += r[i];
}

// ---------------- Anderson update, K previous residuals, per-token LS -----
template <int KA>
__global__ __launch_bounds__(256) void anderson_kernel(
    float* __restrict__ z, const float* __restrict__ rescur,
    const float* __restrict__ p0, const float* __restrict__ p1,
    const float* __restrict__ p2, const float* __restrict__ p3) {
  __shared__ float sbuf[4];
  int row = blockIdx.x, tid = threadIdx.x;
  size_t base = (size_t)row * CDIM + tid;
  float r[3];
#pragma unroll
  for (int i = 0; i < 3; i++) r[i] = rescur[base + i * 256];
  const float* ps[4] = {p0, p1, p2, p3};
  float dF[KA][3];
#pragma unroll
  for (int k = 0; k < KA; k++)
#pragma unroll
    for (int i = 0; i < 3; i++) dF[k][i] = ps[k][base + i * 256] - r[i];

  float Gm[KA][KA], bv[KA];
#pragma unroll
  for (int k = 0; k < KA; k++) {
#pragma unroll
    for (int ll = k; ll < KA; ll++) {
      float p = 0.f;
#pragma unroll
      for (int i = 0; i < 3; i++) p += dF[k][i] * dF[ll][i];
      float t = block_reduce_sum(p, sbuf);
      Gm[k][ll] = t;
      Gm[ll][k] = t;
    }
  }
#pragma unroll
  for (int k = 0; k < KA; k++) Gm[k][k] += 1e-6f;
#pragma unroll
  for (int k = 0; k < KA; k++) {
    float p = 0.f;
#pragma unroll
    for (int i = 0; i < 3; i++) p += dF[k][i] * r[i];
    bv[k] = block_reduce_sum(p, sbuf);
  }
  float alpha[KA];
#pragma unroll
  for (int p = 0; p < KA; p++) {
    float inv = 1.f / Gm[p][p];
#pragma unroll
    for (int rr = p + 1; rr < KA; rr++) {
      float f = Gm[rr][p] * inv;
#pragma unroll
      for (int c = p; c < KA; c++) Gm[rr][c] -= f * Gm[p][c];
      bv[rr] -= f * bv[p];
    }
  }
#pragma unroll
  for (int p = KA - 1; p >= 0; p--) {
    float s2 = bv[p];
#pragma unroll
    for (int c = p + 1; c < KA; c++) s2 -= Gm[p][c] * alpha[c];
    alpha[p] = s2 / Gm[p][p];
  }
#pragma unroll
  for (int i = 0; i < 3; i++) {
    float d = r[i];
#pragma unroll
    for (int k = 0; k < KA; k++) d = fmaf(-dF[k][i], alpha[k], d);
    z[base + i * 256] += d;
  }
}

extern "C" void kernel_launch(void* const* d_in, const int* in_sizes, int n_in,
                              void* d_out, int out_size, void* d_ws,
                              size_t ws_size, hipStream_t stream) {
  (void)in_sizes; (void)n_in; (void)out_size; (void)ws_size;
  const float* u = (const float*)d_in[0];
  const float* iter_emb = (const float*)d_in[1];
  const float* ln1w = (const float*)d_in[2];
  const float* ln1b = (const float*)d_in[3];
  const float* wqkv = (const float*)d_in[4];
  const float* bqkv = (const float*)d_in[5];
  const float* wo = (const float*)d_in[6];
  const float* bo = (const float*)d_in[7];
  const float* ln2w = (const float*)d_in[8];
  const float* ln2b = (const float*)d_in[9];
  const float* w1 = (const float*)d_in[10];
  const float* b1 = (const float*)d_in[11];
  const float* w2 = (const float*)d_in[12];
  const float* b2 = (const float*)d_in[13];

  const size_t S = (size_t)BT * CDIM;  // 3,145,728
  float* ws = (float*)d_ws;
  // fp32 slots:
  float* z = ws + 0 * S;
  float* zattn = ws + 1 * S;
  float* res[5] = {ws + 2 * S, ws + 3 * S, ws + 4 * S, ws + 5 * S, ws + 6 * S};
  // f16 region:
  f16* q_h = (f16*)(ws + 7 * S);   // S f16: [7.0,7.5)   [B,H,T,64]
  f16* k_h = q_h + S;              // [7.5,8.0)          [B,H,T,64]
  f16* vt_h = q_h + 2 * S;         // [8.0,8.5)          [B,H,64,T]
  f16* h_h = (f16*)(ws + 7 * S);   // 4S f16 [7.0,9.0) — aliases q/k/vt
                                   // (disjoint lifetime: mlp1..mlp2 only)
  f16* x_h = (f16*)(ws + 9 * S);   // S f16 [9.0,9.5): LN out / attn out
  f16* wqkv_h = x_h + S;
  f16* wo_h = wqkv_h + (size_t)3 * CDIM * CDIM;
  f16* w1_h = wo_h + (size_t)CDIM * CDIM;
  f16* w2_h = w1_h + (size_t)4 * CDIM * CDIM;

  cvt_f16_kernel<<<1728, 256, 0, stream>>>(wqkv, wqkv_h);
  cvt_f16_kernel<<<576, 256, 0, stream>>>(wo, wo_h);
  cvt_f16_kernel<<<2304, 256, 0, stream>>>(w1, w1_h);
  cvt_f16_kernel<<<2304, 256, 0, stream>>>(w2, w2_h);
  zero_kernel<<<S / 1024, 256, 0, stream>>>((float4*)z);

  for (int it = 0; it < 6; it++) {
    ln1_kernel<<<BT, 256, 0, stream>>>(z, u, iter_emb + it * CDIM, ln1w, ln1b,
                                       x_h);
    gemm_qkv<<<dim3(18, 64), 256, 0, stream>>>(x_h, wqkv_h, bqkv, q_h, k_h,
                                               vt_h, CDIM);
    flash_attn6<<<dim3(BBATCH * NHEAD, TSEQ / 64), 256, 0, stream>>>(
        q_h, k_h, vt_h, x_h);
    gemm_mfma64<0><<<dim3(12, 64), 256, 0, stream>>>(
        x_h, wo_h, bo, z, nullptr, zattn, BT, CDIM, CDIM);
    ln2_kernel<<<BT, 256, 0, stream>>>(zattn, ln2w, ln2b, x_h);
    gemm_mfma<1><<<dim3(24, 32), 256, 0, stream>>>(
        x_h, w1_h, b1, h_h, BT, 4 * CDIM, CDIM);
    float* rcur = res[it % 5];
    gemm_mfma64<2><<<dim3(12, 64), 256, 0, stream>>>(
        h_h, w2_h, b2, zattn, z, rcur, BT, CDIM, 4 * CDIM);

    int Kh = it < 4 ? it : 4;
    if (Kh == 0) {
      add_res_kernel<<<S / 256, 256, 0, stream>>>(z, rcur);
    } else {
      const float* p[4] = {rcur, rcur, rcur, rcur};
      for (int kx = 1; kx <= Kh; kx++) p[kx - 1] = res[(it - kx) % 5];
      switch (Kh) {
        case 1: anderson_kernel<1><<<BT, 256, 0, stream>>>(z, rcur, p[0], p[1], p[2], p[3]); break;
        case 2: anderson_kernel<2><<<BT, 256, 0, stream>>>(z, rcur, p[0], p[1], p[2], p[3]); break;
        case 3: anderson_kernel<3><<<BT, 256, 0, stream>>>(z, rcur, p[0], p[1], p[2], p[3]); break;
        default: anderson_kernel<4><<<BT, 256, 0, stream>>>(z, rcur, p[0], p[1], p[2], p[3]); break;
      }
    }
  }
  hipMemcpyAsync(d_out, z, S * sizeof(float), hipMemcpyDeviceToDevice, stream);
}

// Round 10
// 1729.008 us; speedup vs baseline: 1.0416x; 1.0416x over previous
//
#include <hip/hip_runtime.h>
#include <math.h>

#define BT 4096
#define CDIM 768
#define NHEAD 12
#define DH 64
#define TSEQ 1024
#define BBATCH 4

typedef _Float16 f16;
typedef __attribute__((ext_vector_type(4))) _Float16 f16x4;
typedef __attribute__((ext_vector_type(8))) _Float16 f16x8;
typedef __attribute__((ext_vector_type(4))) float f32x4;

__device__ __forceinline__ void gload_lds16(const f16* g, f16* l) {
  __builtin_amdgcn_global_load_lds(
      (const __attribute__((address_space(1))) unsigned*)(const void*)g,
      (__attribute__((address_space(3))) unsigned*)(void*)l, 16, 0, 0);
}

// ---------------- block reduction (256 threads = 4 waves) ----------------
__device__ __forceinline__ float block_reduce_sum(float v, float* sbuf) {
#pragma unroll
  for (int o = 32; o > 0; o >>= 1) v += __shfl_down(v, o, 64);
  int lane = threadIdx.x & 63;
  int w = threadIdx.x >> 6;
  if (lane == 0) sbuf[w] = v;
  __syncthreads();
  float r = sbuf[0] + sbuf[1] + sbuf[2] + sbuf[3];
  __syncthreads();
  return r;
}

// ---------------- zero-fill ----------------------------------------------
__global__ __launch_bounds__(256) void zero_kernel(float4* __restrict__ p) {
  p[(size_t)blockIdx.x * 256 + threadIdx.x] = make_float4(0.f, 0.f, 0.f, 0.f);
}

// ---------------- fp32 -> fp16 weight conversion (4 elems/thread) --------
__global__ __launch_bounds__(256) void cvt_f16_kernel(
    const float* __restrict__ in, f16* __restrict__ out) {
  size_t i = ((size_t)blockIdx.x * 256 + threadIdx.x) * 4;
  float4 v = *(const float4*)(in + i);
  f16x4 o = {(f16)v.x, (f16)v.y, (f16)v.z, (f16)v.w};
  *(f16x4*)(out + i) = o;
}

// ---------------- LN1: x_h = f16(LN(z + 0.1*emb + u) * w + b) ------------
__global__ __launch_bounds__(256) void ln1_kernel(
    const float* __restrict__ z, const float* __restrict__ u,
    const float* __restrict__ emb, const float* __restrict__ w,
    const float* __restrict__ b, f16* __restrict__ x) {
  __shared__ float sbuf[4];
  int row = blockIdx.x;
  int tid = threadIdx.x;
  const float* zr = z + (size_t)row * CDIM;
  const float* ur = u + (size_t)row * CDIM;
  float v[3];
  float s = 0.f;
#pragma unroll
  for (int i = 0; i < 3; i++) {
    int c = tid + i * 256;
    v[i] = zr[c] + 0.1f * emb[c] + ur[c];
    s += v[i];
  }
  s = block_reduce_sum(s, sbuf);
  float mu = s * (1.f / CDIM);
  float sq = 0.f;
#pragma unroll
  for (int i = 0; i < 3; i++) { v[i] -= mu; sq += v[i] * v[i]; }
  sq = block_reduce_sum(sq, sbuf);
  float rstd = rsqrtf(sq * (1.f / CDIM) + 1e-5f);
  f16* xr = x + (size_t)row * CDIM;
#pragma unroll
  for (int i = 0; i < 3; i++) {
    int c = tid + i * 256;
    xr[c] = (f16)(v[i] * rstd * w[c] + b[c]);
  }
}

// ---------------- LN2 ----------------------------------------------------
__global__ __launch_bounds__(256) void ln2_kernel(
    const float* __restrict__ in, const float* __restrict__ w,
    const float* __restrict__ b, f16* __restrict__ x) {
  __shared__ float sbuf[4];
  int row = blockIdx.x;
  int tid = threadIdx.x;
  const float* ir = in + (size_t)row * CDIM;
  float v[3];
  float s = 0.f;
#pragma unroll
  for (int i = 0; i < 3; i++) {
    int c = tid + i * 256;
    v[i] = ir[c];
    s += v[i];
  }
  s = block_reduce_sum(s, sbuf);
  float mu = s * (1.f / CDIM);
  float sq = 0.f;
#pragma unroll
  for (int i = 0; i < 3; i++) { v[i] -= mu; sq += v[i] * v[i]; }
  sq = block_reduce_sum(sq, sbuf);
  float rstd = rsqrtf(sq * (1.f / CDIM) + 1e-5f);
  f16* xr = x + (size_t)row * CDIM;
#pragma unroll
  for (int i = 0; i < 3; i++) {
    int c = tid + i * 256;
    xr[c] = (f16)(v[i] * rstd * w[c] + b[c]);
  }
}

__device__ __forceinline__ float gelu_exact(float t) {
  return 0.5f * t * (1.f + erff(t * 0.70710678118654752f));
}

// ---------------- fp16 MFMA GEMM 128x128 (m97 structure) -----------------
// __launch_bounds__(256,3): 3 blocks/CU, VGPR budget ~170 (m97 point: 164
// VGPR, 874 TF). Default heuristic capped VGPRs and spilled acc/frags.
// MODE 1: hout  = f16(gelu(acc + bias))            (mlp1)
// MODE 3: scatter f16 q/k to [B,H,T,64], v transposed to [B,H,64,T]
template <int MODE>
__global__ __launch_bounds__(256, 3) void gemm_mfma(
    const f16* __restrict__ A, const f16* __restrict__ W,
    const float* __restrict__ bias, f16* __restrict__ hq,
    f16* __restrict__ hk, f16* __restrict__ hvt, f16* __restrict__ hout,
    int M, int N, int K) {
  __shared__ __align__(16) f16 As[128 * 32];
  __shared__ __align__(16) f16 Bs[128 * 32];
  int tid = threadIdx.x;
  int wv = tid >> 6, lane = tid & 63;
  int bm = blockIdx.y, bn = blockIdx.x;
  int wm = (wv >> 1) * 64, wn = (wv & 1) * 64;

  int srow = wv * 16 + (lane >> 2);
  int scol = (lane & 3) * 8;
  const f16* gA = A + (size_t)(bm * 128 + srow) * K + scol;
  const f16* gB = W + (size_t)(bn * 128 + srow) * K + scol;
  f16* lA = As + wv * 16 * 32;
  f16* lB = Bs + wv * 16 * 32;

  f32x4 acc[4][4];
#pragma unroll
  for (int i = 0; i < 4; i++)
#pragma unroll
    for (int j = 0; j < 4; j++) acc[i][j] = (f32x4){0.f, 0.f, 0.f, 0.f};

  int arow = lane & 15;
  int koff = (lane >> 4) * 8;

  for (int k0 = 0; k0 < K; k0 += 32) {
    __syncthreads();
    gload_lds16(gA + k0, lA);
    gload_lds16(gA + (size_t)64 * K + k0, lA + 64 * 32);
    gload_lds16(gB + k0, lB);
    gload_lds16(gB + (size_t)64 * K + k0, lB + 64 * 32);
    __syncthreads();
    f16x8 af[4], bfr[4];
#pragma unroll
    for (int mi = 0; mi < 4; mi++)
      af[mi] = *(const f16x8*)&As[(wm + mi * 16 + arow) * 32 + koff];
#pragma unroll
    for (int nj = 0; nj < 4; nj++)
      bfr[nj] = *(const f16x8*)&Bs[(wn + nj * 16 + arow) * 32 + koff];
#pragma unroll
    for (int mi = 0; mi < 4; mi++)
#pragma unroll
      for (int nj = 0; nj < 4; nj++)
        acc[mi][nj] = __builtin_amdgcn_mfma_f32_16x16x32_f16(
            af[mi], bfr[nj], acc[mi][nj], 0, 0, 0);
  }

  // C/D layout: col = lane&15, row = (lane>>4)*4 + reg
  int crow0 = bm * 128 + wm + (lane >> 4) * 4;
  int ccol0 = bn * 128 + wn + (lane & 15);
#pragma unroll
  for (int nj = 0; nj < 4; nj++) {
    int col = ccol0 + nj * 16;
    float bcol = bias[col];
    if constexpr (MODE == 3) {
      int which = col / CDIM;
      int rem = col - which * CDIM;
      int h = rem >> 6;
      int d = rem & 63;
#pragma unroll
      for (int mi = 0; mi < 4; mi++) {
#pragma unroll
        for (int r = 0; r < 4; r++) {
          int m = crow0 + mi * 16 + r;
          int bb = m >> 10, t = m & 1023;
          f16 val = (f16)(acc[mi][nj][r] + bcol);
          if (which == 0)
            hq[(((size_t)(bb * NHEAD + h) * TSEQ + t) << 6) + d] = val;
          else if (which == 1)
            hk[(((size_t)(bb * NHEAD + h) * TSEQ + t) << 6) + d] = val;
          else
            hvt[(((size_t)(bb * NHEAD + h) * DH + d) << 10) + t] = val;
        }
      }
    } else {  // MODE 1
#pragma unroll
      for (int mi = 0; mi < 4; mi++) {
#pragma unroll
        for (int r = 0; r < 4; r++) {
          int m = crow0 + mi * 16 + r;
          size_t idx = (size_t)m * N + col;
          hout[idx] = (f16)gelu_exact(acc[mi][nj][r] + bcol);
        }
      }
    }
  }
}

// ---------------- fp16 MFMA GEMM 64x64 (occupancy variant, N=768 GEMMs) --
// (256,4): 4 blocks/CU, VGPR budget 128 (needs ~70, no spill).
// MODE 0: fout0 = acc + bias + aux1               (out-proj residual)
// MODE 2: fout0 = acc + bias + aux1 - aux2        (mlp2 -> residual F)
template <int MODE>
__global__ __launch_bounds__(256, 4) void gemm_mfma64(
    const f16* __restrict__ A, const f16* __restrict__ W,
    const float* __restrict__ bias, const float* __restrict__ aux1,
    const float* __restrict__ aux2, float* __restrict__ fout0,
    int M, int N, int K) {
  __shared__ __align__(16) f16 As[64 * 32];
  __shared__ __align__(16) f16 Bs[64 * 32];
  int tid = threadIdx.x;
  int wv = tid >> 6, lane = tid & 63;
  int bm = blockIdx.y, bn = blockIdx.x;
  int wm = (wv >> 1) * 32, wn = (wv & 1) * 32;

  int srow = wv * 16 + (lane >> 2);
  int scol = (lane & 3) * 8;
  const f16* gA = A + (size_t)(bm * 64 + srow) * K + scol;
  const f16* gB = W + (size_t)(bn * 64 + srow) * K + scol;
  f16* lA = As + wv * 16 * 32;
  f16* lB = Bs + wv * 16 * 32;

  f32x4 acc[2][2];
#pragma unroll
  for (int i = 0; i < 2; i++)
#pragma unroll
    for (int j = 0; j < 2; j++) acc[i][j] = (f32x4){0.f, 0.f, 0.f, 0.f};

  int arow = lane & 15;
  int koff = (lane >> 4) * 8;

  for (int k0 = 0; k0 < K; k0 += 32) {
    __syncthreads();
    gload_lds16(gA + k0, lA);
    gload_lds16(gB + k0, lB);
    __syncthreads();
    f16x8 af[2], bfr[2];
#pragma unroll
    for (int mi = 0; mi < 2; mi++)
      af[mi] = *(const f16x8*)&As[(wm + mi * 16 + arow) * 32 + koff];
#pragma unroll
    for (int nj = 0; nj < 2; nj++)
      bfr[nj] = *(const f16x8*)&Bs[(wn + nj * 16 + arow) * 32 + koff];
#pragma unroll
    for (int mi = 0; mi < 2; mi++)
#pragma unroll
      for (int nj = 0; nj < 2; nj++)
        acc[mi][nj] = __builtin_amdgcn_mfma_f32_16x16x32_f16(
            af[mi], bfr[nj], acc[mi][nj], 0, 0, 0);
  }

  int crow0 = bm * 64 + wm + (lane >> 4) * 4;
  int ccol0 = bn * 64 + wn + (lane & 15);
#pragma unroll
  for (int nj = 0; nj < 2; nj++) {
    int col = ccol0 + nj * 16;
    float bcol = bias[col];
#pragma unroll
    for (int mi = 0; mi < 2; mi++) {
#pragma unroll
      for (int r = 0; r < 4; r++) {
        int m = crow0 + mi * 16 + r;
        size_t idx = (size_t)m * N + col;
        float val = acc[mi][nj][r] + bcol;
        if constexpr (MODE == 0) {
          fout0[idx] = val + aux1[idx];
        } else {  // MODE 2
          fout0[idx] = val + aux1[idx] - aux2[idx];
        }
      }
    }
  }
}

// ---------------- MFMA flash attention v7: unspilled ----------------------
// Root-cause fix for the R6-R9 ~95 us plateau: default compilation capped
// VGPRs at 52-68 while the loop keeps ~120-150 live -> scratch spills every
// iteration (200-900 cyc each) dominated. __launch_bounds__(256,3) gives a
// ~170-VGPR budget (3 blocks/CU = 12 waves, same as measured occupancy).
// K loads inline (no double-buffer: K/V are L2-local after the XCD swizzle,
// and dropping kn[] keeps the live set ~120 regs). V issued before exp/P.
// Fixed-shift softmax; P round-trips LDS (PSTRIDE=72, 16B-aligned rows).
#define PSTRIDE 72
__global__ __launch_bounds__(256, 3) void flash_attn7(
    const f16* __restrict__ Qg, const f16* __restrict__ Kg,
    const f16* __restrict__ Vt, f16* __restrict__ attn) {
  __shared__ __align__(16) f16 Plds[4][16 * PSTRIDE];
  int wv = threadIdx.x >> 6, lane = threadIdx.x & 63;
  int bh = blockIdx.x;  // bh fastest: 16 blocks sharing K/V land on one XCD
  int bb = bh / NHEAD, h = bh % NHEAD;
  int m0 = (blockIdx.y * 4 + wv) * 16;
  int am = lane & 15;
  int quad = lane >> 4;
  int ak = quad * 8;

  const f16* qbase = Qg + (((size_t)bh * TSEQ + m0) << 6);
  f16x8 qf0 = *(const f16x8*)(qbase + am * 64 + ak);
  f16x8 qf1 = *(const f16x8*)(qbase + am * 64 + 32 + ak);
#pragma unroll
  for (int i = 0; i < 8; i++) { qf0[i] *= (f16)0.125f; qf1[i] *= (f16)0.125f; }

  const f16* kb = Kg + (((size_t)bh * TSEQ) << 6);
  const f16* vb = Vt + (((size_t)bh * DH) << 10);
  f16* Pw = Plds[wv];

  f32x4 Oa[4];
#pragma unroll
  for (int i = 0; i < 4; i++) Oa[i] = (f32x4){0.f, 0.f, 0.f, 0.f};
  float lpart[4] = {0.f, 0.f, 0.f, 0.f};

  for (int n0 = 0; n0 < TSEQ; n0 += 64) {
    // ---- S = Q K^T (K frags inline; L2-hit latency, 4 indep chains) ----
    f32x4 S[4];
#pragma unroll
    for (int t = 0; t < 4; t++) {
      const f16* kr = kb + (((size_t)(n0 + 16 * t + am)) << 6);
      f16x8 kf0 = *(const f16x8*)(kr + ak);
      f16x8 kf1 = *(const f16x8*)(kr + 32 + ak);
      S[t] = __builtin_amdgcn_mfma_f32_16x16x32_f16(
          qf0, kf0, (f32x4){0.f, 0.f, 0.f, 0.f}, 0, 0, 0);
      S[t] = __builtin_amdgcn_mfma_f32_16x16x32_f16(qf1, kf1, S[t], 0, 0, 0);
    }
    // issue V loads now — latency hidden behind the exp/P phase
    f16x8 vf0[4], vf1[4];
#pragma unroll
    for (int dt = 0; dt < 4; dt++) {
      const f16* vr = vb + (((size_t)(16 * dt + am)) << 10) + n0;
      vf0[dt] = *(const f16x8*)(vr + ak);
      vf1[dt] = *(const f16x8*)(vr + 32 + ak);
    }
    // ---- p = exp(s) (fixed shift), accumulate l, stage P to LDS ----
#pragma unroll
    for (int t = 0; t < 4; t++) {
#pragma unroll
      for (int r = 0; r < 4; r++) {
        float p = __expf(S[t][r]);
        lpart[r] += p;
        Pw[(quad * 4 + r) * PSTRIDE + 16 * t + am] = (f16)p;
      }
    }
    // ---- P (A-layout from LDS; compiler orders vs the writes) @ V ----
    f16x8 pa0 = *(const f16x8*)&Pw[am * PSTRIDE + ak];
    f16x8 pa1 = *(const f16x8*)&Pw[am * PSTRIDE + 32 + ak];
#pragma unroll
    for (int dt = 0; dt < 4; dt++) {
      Oa[dt] = __builtin_amdgcn_mfma_f32_16x16x32_f16(pa0, vf0[dt], Oa[dt], 0, 0, 0);
      Oa[dt] = __builtin_amdgcn_mfma_f32_16x16x32_f16(pa1, vf1[dt], Oa[dt], 0, 0, 0);
    }
  }

  // ---- single final l reduction across the 16 lanes of each quad-row ----
#pragma unroll
  for (int o = 1; o < 16; o <<= 1)
#pragma unroll
    for (int r = 0; r < 4; r++) lpart[r] += __shfl_xor(lpart[r], o, 64);

  // ---- epilogue: O[m][d] / l -> attn (f16 [B,T,C] at col h*64+d) ----
#pragma unroll
  for (int r = 0; r < 4; r++) {
    int m = m0 + quad * 4 + r;
    float inv = 1.f / lpart[r];
    f16* orow = attn + ((size_t)(bb * TSEQ + m)) * CDIM + h * DH;
#pragma unroll
    for (int dt = 0; dt < 4; dt++)
      orow[dt * 16 + am] = (f16)(Oa[dt][r] * inv);
  }
}

// ---------------- Anderson: first iteration (K=0): z += res --------------
__global__ __launch_bounds__(256) void add_res_kernel(
    float* __restrict__ z, const float* __restrict__ r) {
  size_t i = (size_t)blockIdx.x * 256 + threadIdx.x;
  z[i] += r[i];
}

// ---------------- Anderson update, K previous residuals, per-token LS -----
template <int KA>
__global__ __launch_bounds__(256) void anderson_kernel(
    float* __restrict__ z, const float* __restrict__ rescur,
    const float* __restrict__ p0, const float* __restrict__ p1,
    const float* __restrict__ p2, const float* __restrict__ p3) {
  __shared__ float sbuf[4];
  int row = blockIdx.x, tid = threadIdx.x;
  size_t base = (size_t)row * CDIM + tid;
  float r[3];
#pragma unroll
  for (int i = 0; i < 3; i++) r[i] = rescur[base + i * 256];
  const float* ps[4] = {p0, p1, p2, p3};
  float dF[KA][3];
#pragma unroll
  for (int k = 0; k < KA; k++)
#pragma unroll
    for (int i = 0; i < 3; i++) dF[k][i] = ps[k][base + i * 256] - r[i];

  float Gm[KA][KA], bv[KA];
#pragma unroll
  for (int k = 0; k < KA; k++) {
#pragma unroll
    for (int ll = k; ll < KA; ll++) {
      float p = 0.f;
#pragma unroll
      for (int i = 0; i < 3; i++) p += dF[k][i] * dF[ll][i];
      float t = block_reduce_sum(p, sbuf);
      Gm[k][ll] = t;
      Gm[ll][k] = t;
    }
  }
#pragma unroll
  for (int k = 0; k < KA; k++) Gm[k][k] += 1e-6f;
#pragma unroll
  for (int k = 0; k < KA; k++) {
    float p = 0.f;
#pragma unroll
    for (int i = 0; i < 3; i++) p += dF[k][i] * r[i];
    bv[k] = block_reduce_sum(p, sbuf);
  }
  float alpha[KA];
#pragma unroll
  for (int p = 0; p < KA; p++) {
    float inv = 1.f / Gm[p][p];
#pragma unroll
    for (int rr = p + 1; rr < KA; rr++) {
      float f = Gm[rr][p] * inv;
#pragma unroll
      for (int c = p; c < KA; c++) Gm[rr][c] -= f * Gm[p][c];
      bv[rr] -= f * bv[p];
    }
  }
#pragma unroll
  for (int p = KA - 1; p >= 0; p--) {
    float s2 = bv[p];
#pragma unroll
    for (int c = p + 1; c < KA; c++) s2 -= Gm[p][c] * alpha[c];
    alpha[p] = s2 / Gm[p][p];
  }
#pragma unroll
  for (int i = 0; i < 3; i++) {
    float d = r[i];
#pragma unroll
    for (int k = 0; k < KA; k++) d = fmaf(-dF[k][i], alpha[k], d);
    z[base + i * 256] += d;
  }
}

extern "C" void kernel_launch(void* const* d_in, const int* in_sizes, int n_in,
                              void* d_out, int out_size, void* d_ws,
                              size_t ws_size, hipStream_t stream) {
  (void)in_sizes; (void)n_in; (void)out_size; (void)ws_size;
  const float* u = (const float*)d_in[0];
  const float* iter_emb = (const float*)d_in[1];
  const float* ln1w = (const float*)d_in[2];
  const float* ln1b = (const float*)d_in[3];
  const float* wqkv = (const float*)d_in[4];
  const float* bqkv = (const float*)d_in[5];
  const float* wo = (const float*)d_in[6];
  const float* bo = (const float*)d_in[7];
  const float* ln2w = (const float*)d_in[8];
  const float* ln2b = (const float*)d_in[9];
  const float* w1 = (const float*)d_in[10];
  const float* b1 = (const float*)d_in[11];
  const float* w2 = (const float*)d_in[12];
  const float* b2 = (const float*)d_in[13];

  const size_t S = (size_t)BT * CDIM;  // 3,145,728
  float* ws = (float*)d_ws;
  // fp32 slots:
  float* z = ws + 0 * S;
  float* zattn = ws + 1 * S;
  float* res[5] = {ws + 2 * S, ws + 3 * S, ws + 4 * S, ws + 5 * S, ws + 6 * S};
  // f16 region:
  f16* q_h = (f16*)(ws + 7 * S);   // S f16: [7.0,7.5)   [B,H,T,64]
  f16* k_h = q_h + S;              // [7.5,8.0)          [B,H,T,64]
  f16* vt_h = q_h + 2 * S;         // [8.0,8.5)          [B,H,64,T]
  f16* h_h = (f16*)(ws + 7 * S);   // 4S f16 [7.0,9.0) — aliases q/k/vt
                                   // (disjoint lifetime: mlp1..mlp2 only)
  f16* x_h = (f16*)(ws + 9 * S);   // S f16 [9.0,9.5): LN out / attn out
  f16* wqkv_h = x_h + S;
  f16* wo_h = wqkv_h + (size_t)3 * CDIM * CDIM;
  f16* w1_h = wo_h + (size_t)CDIM * CDIM;
  f16* w2_h = w1_h + (size_t)4 * CDIM * CDIM;

  cvt_f16_kernel<<<1728, 256, 0, stream>>>(wqkv, wqkv_h);
  cvt_f16_kernel<<<576, 256, 0, stream>>>(wo, wo_h);
  cvt_f16_kernel<<<2304, 256, 0, stream>>>(w1, w1_h);
  cvt_f16_kernel<<<2304, 256, 0, stream>>>(w2, w2_h);
  zero_kernel<<<S / 1024, 256, 0, stream>>>((float4*)z);

  for (int it = 0; it < 6; it++) {
    ln1_kernel<<<BT, 256, 0, stream>>>(z, u, iter_emb + it * CDIM, ln1w, ln1b,
                                       x_h);
    gemm_mfma<3><<<dim3(18, 32), 256, 0, stream>>>(
        x_h, wqkv_h, bqkv, q_h, k_h, vt_h, nullptr, BT, 3 * CDIM, CDIM);
    flash_attn7<<<dim3(BBATCH * NHEAD, TSEQ / 64), 256, 0, stream>>>(
        q_h, k_h, vt_h, x_h);
    gemm_mfma64<0><<<dim3(12, 64), 256, 0, stream>>>(
        x_h, wo_h, bo, z, nullptr, zattn, BT, CDIM, CDIM);
    ln2_kernel<<<BT, 256, 0, stream>>>(zattn, ln2w, ln2b, x_h);
    gemm_mfma<1><<<dim3(24, 32), 256, 0, stream>>>(
        x_h, w1_h, b1, nullptr, nullptr, nullptr, h_h, BT, 4 * CDIM, CDIM);
    float* rcur = res[it % 5];
    gemm_mfma64<2><<<dim3(12, 64), 256, 0, stream>>>(
        h_h, w2_h, b2, zattn, z, rcur, BT, CDIM, 4 * CDIM);

    int Kh = it < 4 ? it : 4;
    if (Kh == 0) {
      add_res_kernel<<<S / 256, 256, 0, stream>>>(z, rcur);
    } else {
      const float* p[4] = {rcur, rcur, rcur, rcur};
      for (int kx = 1; kx <= Kh; kx++) p[kx - 1] = res[(it - kx) % 5];
      switch (Kh) {
        case 1: anderson_kernel<1><<<BT, 256, 0, stream>>>(z, rcur, p[0], p[1], p[2], p[3]); break;
        case 2: anderson_kernel<2><<<BT, 256, 0, stream>>>(z, rcur, p[0], p[1], p[2], p[3]); break;
        case 3: anderson_kernel<3><<<BT, 256, 0, stream>>>(z, rcur, p[0], p[1], p[2], p[3]); break;
        default: anderson_kernel<4><<<BT, 256, 0, stream>>>(z, rcur, p[0], p[1], p[2], p[3]); break;
      }
    }
  }
  hipMemcpyAsync(d_out, z, S * sizeof(float), hipMemcpyDeviceToDevice, stream);
}

// Round 11
// 1373.613 us; speedup vs baseline: 1.3111x; 1.2587x over previous
//
#include <hip/hip_runtime.h>
#include <math.h>

#define BT 4096
#define CDIM 768
#define NHEAD 12
#define DH 64
#define TSEQ 1024
#define BBATCH 4

typedef _Float16 f16;
typedef __attribute__((ext_vector_type(4))) _Float16 f16x4;
typedef __attribute__((ext_vector_type(8))) _Float16 f16x8;
typedef __attribute__((ext_vector_type(4))) float f32x4;

__device__ __forceinline__ void gload_lds16(const f16* g, f16* l) {
  __builtin_amdgcn_global_load_lds(
      (const __attribute__((address_space(1))) unsigned*)(const void*)g,
      (__attribute__((address_space(3))) unsigned*)(void*)l, 16, 0, 0);
}

// ---------------- block reduction (256 threads = 4 waves) ----------------
__device__ __forceinline__ float block_reduce_sum(float v, float* sbuf) {
#pragma unroll
  for (int o = 32; o > 0; o >>= 1) v += __shfl_down(v, o, 64);
  int lane = threadIdx.x & 63;
  int w = threadIdx.x >> 6;
  if (lane == 0) sbuf[w] = v;
  __syncthreads();
  float r = sbuf[0] + sbuf[1] + sbuf[2] + sbuf[3];
  __syncthreads();
  return r;
}

// ---------------- zero-fill ----------------------------------------------
__global__ __launch_bounds__(256) void zero_kernel(float4* __restrict__ p) {
  p[(size_t)blockIdx.x * 256 + threadIdx.x] = make_float4(0.f, 0.f, 0.f, 0.f);
}

// ---------------- fp32 -> fp16 weight conversion (4 elems/thread) --------
__global__ __launch_bounds__(256) void cvt_f16_kernel(
    const float* __restrict__ in, f16* __restrict__ out) {
  size_t i = ((size_t)blockIdx.x * 256 + threadIdx.x) * 4;
  float4 v = *(const float4*)(in + i);
  f16x4 o = {(f16)v.x, (f16)v.y, (f16)v.z, (f16)v.w};
  *(f16x4*)(out + i) = o;
}

// ---------------- LN1: x_h = f16(LN(z + 0.1*emb + u) * w + b) ------------
__global__ __launch_bounds__(256) void ln1_kernel(
    const float* __restrict__ z, const float* __restrict__ u,
    const float* __restrict__ emb, const float* __restrict__ w,
    const float* __restrict__ b, f16* __restrict__ x) {
  __shared__ float sbuf[4];
  int row = blockIdx.x;
  int tid = threadIdx.x;
  const float* zr = z + (size_t)row * CDIM;
  const float* ur = u + (size_t)row * CDIM;
  float v[3];
  float s = 0.f;
#pragma unroll
  for (int i = 0; i < 3; i++) {
    int c = tid + i * 256;
    v[i] = zr[c] + 0.1f * emb[c] + ur[c];
    s += v[i];
  }
  s = block_reduce_sum(s, sbuf);
  float mu = s * (1.f / CDIM);
  float sq = 0.f;
#pragma unroll
  for (int i = 0; i < 3; i++) { v[i] -= mu; sq += v[i] * v[i]; }
  sq = block_reduce_sum(sq, sbuf);
  float rstd = rsqrtf(sq * (1.f / CDIM) + 1e-5f);
  f16* xr = x + (size_t)row * CDIM;
#pragma unroll
  for (int i = 0; i < 3; i++) {
    int c = tid + i * 256;
    xr[c] = (f16)(v[i] * rstd * w[c] + b[c]);
  }
}

// ---------------- LN2 ----------------------------------------------------
__global__ __launch_bounds__(256) void ln2_kernel(
    const float* __restrict__ in, const float* __restrict__ w,
    const float* __restrict__ b, f16* __restrict__ x) {
  __shared__ float sbuf[4];
  int row = blockIdx.x;
  int tid = threadIdx.x;
  const float* ir = in + (size_t)row * CDIM;
  float v[3];
  float s = 0.f;
#pragma unroll
  for (int i = 0; i < 3; i++) {
    int c = tid + i * 256;
    v[i] = ir[c];
    s += v[i];
  }
  s = block_reduce_sum(s, sbuf);
  float mu = s * (1.f / CDIM);
  float sq = 0.f;
#pragma unroll
  for (int i = 0; i < 3; i++) { v[i] -= mu; sq += v[i] * v[i]; }
  sq = block_reduce_sum(sq, sbuf);
  float rstd = rsqrtf(sq * (1.f / CDIM) + 1e-5f);
  f16* xr = x + (size_t)row * CDIM;
#pragma unroll
  for (int i = 0; i < 3; i++) {
    int c = tid + i * 256;
    xr[c] = (f16)(v[i] * rstd * w[c] + b[c]);
  }
}

__device__ __forceinline__ float gelu_exact(float t) {
  return 0.5f * t * (1.f + erff(t * 0.70710678118654752f));
}

// ---------------- fp16 MFMA GEMM 128x128 (m97 structure) -----------------
// MODE 1: hout  = f16(gelu(acc + bias))            (mlp1)
// MODE 3: scatter f16 q/k to [B,H,T,64], v transposed to [B,H,64,T]
template <int MODE>
__global__ __launch_bounds__(256, 3) void gemm_mfma(
    const f16* __restrict__ A, const f16* __restrict__ W,
    const float* __restrict__ bias, f16* __restrict__ hq,
    f16* __restrict__ hk, f16* __restrict__ hvt, f16* __restrict__ hout,
    int M, int N, int K) {
  __shared__ __align__(16) f16 As[128 * 32];
  __shared__ __align__(16) f16 Bs[128 * 32];
  int tid = threadIdx.x;
  int wv = tid >> 6, lane = tid & 63;
  int bm = blockIdx.y, bn = blockIdx.x;
  int wm = (wv >> 1) * 64, wn = (wv & 1) * 64;

  int srow = wv * 16 + (lane >> 2);
  int scol = (lane & 3) * 8;
  const f16* gA = A + (size_t)(bm * 128 + srow) * K + scol;
  const f16* gB = W + (size_t)(bn * 128 + srow) * K + scol;
  f16* lA = As + wv * 16 * 32;
  f16* lB = Bs + wv * 16 * 32;

  f32x4 acc[4][4];
#pragma unroll
  for (int i = 0; i < 4; i++)
#pragma unroll
    for (int j = 0; j < 4; j++) acc[i][j] = (f32x4){0.f, 0.f, 0.f, 0.f};

  int arow = lane & 15;
  int koff = (lane >> 4) * 8;

  for (int k0 = 0; k0 < K; k0 += 32) {
    __syncthreads();
    gload_lds16(gA + k0, lA);
    gload_lds16(gA + (size_t)64 * K + k0, lA + 64 * 32);
    gload_lds16(gB + k0, lB);
    gload_lds16(gB + (size_t)64 * K + k0, lB + 64 * 32);
    __syncthreads();
    f16x8 af[4], bfr[4];
#pragma unroll
    for (int mi = 0; mi < 4; mi++)
      af[mi] = *(const f16x8*)&As[(wm + mi * 16 + arow) * 32 + koff];
#pragma unroll
    for (int nj = 0; nj < 4; nj++)
      bfr[nj] = *(const f16x8*)&Bs[(wn + nj * 16 + arow) * 32 + koff];
#pragma unroll
    for (int mi = 0; mi < 4; mi++)
#pragma unroll
      for (int nj = 0; nj < 4; nj++)
        acc[mi][nj] = __builtin_amdgcn_mfma_f32_16x16x32_f16(
            af[mi], bfr[nj], acc[mi][nj], 0, 0, 0);
  }

  // C/D layout: col = lane&15, row = (lane>>4)*4 + reg
  int crow0 = bm * 128 + wm + (lane >> 4) * 4;
  int ccol0 = bn * 128 + wn + (lane & 15);
#pragma unroll
  for (int nj = 0; nj < 4; nj++) {
    int col = ccol0 + nj * 16;
    float bcol = bias[col];
    if constexpr (MODE == 3) {
      int which = col / CDIM;
      int rem = col - which * CDIM;
      int h = rem >> 6;
      int d = rem & 63;
#pragma unroll
      for (int mi = 0; mi < 4; mi++) {
#pragma unroll
        for (int r = 0; r < 4; r++) {
          int m = crow0 + mi * 16 + r;
          int bb = m >> 10, t = m & 1023;
          f16 val = (f16)(acc[mi][nj][r] + bcol);
          if (which == 0)
            hq[(((size_t)(bb * NHEAD + h) * TSEQ + t) << 6) + d] = val;
          else if (which == 1)
            hk[(((size_t)(bb * NHEAD + h) * TSEQ + t) << 6) + d] = val;
          else
            hvt[(((size_t)(bb * NHEAD + h) * DH + d) << 10) + t] = val;
        }
      }
    } else {  // MODE 1
#pragma unroll
      for (int mi = 0; mi < 4; mi++) {
#pragma unroll
        for (int r = 0; r < 4; r++) {
          int m = crow0 + mi * 16 + r;
          size_t idx = (size_t)m * N + col;
          hout[idx] = (f16)gelu_exact(acc[mi][nj][r] + bcol);
        }
      }
    }
  }
}

// ---------------- fp16 MFMA GEMM 64x64 (occupancy variant, N=768 GEMMs) --
// MODE 0: fout0 = acc + bias + aux1               (out-proj residual)
// MODE 2: fout0 = acc + bias + aux1 - aux2        (mlp2 -> residual F)
template <int MODE>
__global__ __launch_bounds__(256, 4) void gemm_mfma64(
    const f16* __restrict__ A, const f16* __restrict__ W,
    const float* __restrict__ bias, const float* __restrict__ aux1,
    const float* __restrict__ aux2, float* __restrict__ fout0,
    int M, int N, int K) {
  __shared__ __align__(16) f16 As[64 * 32];
  __shared__ __align__(16) f16 Bs[64 * 32];
  int tid = threadIdx.x;
  int wv = tid >> 6, lane = tid & 63;
  int bm = blockIdx.y, bn = blockIdx.x;
  int wm = (wv >> 1) * 32, wn = (wv & 1) * 32;

  int srow = wv * 16 + (lane >> 2);
  int scol = (lane & 3) * 8;
  const f16* gA = A + (size_t)(bm * 64 + srow) * K + scol;
  const f16* gB = W + (size_t)(bn * 64 + srow) * K + scol;
  f16* lA = As + wv * 16 * 32;
  f16* lB = Bs + wv * 16 * 32;

  f32x4 acc[2][2];
#pragma unroll
  for (int i = 0; i < 2; i++)
#pragma unroll
    for (int j = 0; j < 2; j++) acc[i][j] = (f32x4){0.f, 0.f, 0.f, 0.f};

  int arow = lane & 15;
  int koff = (lane >> 4) * 8;

  for (int k0 = 0; k0 < K; k0 += 32) {
    __syncthreads();
    gload_lds16(gA + k0, lA);
    gload_lds16(gB + k0, lB);
    __syncthreads();
    f16x8 af[2], bfr[2];
#pragma unroll
    for (int mi = 0; mi < 2; mi++)
      af[mi] = *(const f16x8*)&As[(wm + mi * 16 + arow) * 32 + koff];
#pragma unroll
    for (int nj = 0; nj < 2; nj++)
      bfr[nj] = *(const f16x8*)&Bs[(wn + nj * 16 + arow) * 32 + koff];
#pragma unroll
    for (int mi = 0; mi < 2; mi++)
#pragma unroll
      for (int nj = 0; nj < 2; nj++)
        acc[mi][nj] = __builtin_amdgcn_mfma_f32_16x16x32_f16(
            af[mi], bfr[nj], acc[mi][nj], 0, 0, 0);
  }

  int crow0 = bm * 64 + wm + (lane >> 4) * 4;
  int ccol0 = bn * 64 + wn + (lane & 15);
#pragma unroll
  for (int nj = 0; nj < 2; nj++) {
    int col = ccol0 + nj * 16;
    float bcol = bias[col];
#pragma unroll
    for (int mi = 0; mi < 2; mi++) {
#pragma unroll
      for (int r = 0; r < 4; r++) {
        int m = crow0 + mi * 16 + r;
        size_t idx = (size_t)m * N + col;
        float val = acc[mi][nj][r] + bcol;
        if constexpr (MODE == 0) {
          fout0[idx] = val + aux1[idx];
        } else {  // MODE 2
          fout0[idx] = val + aux1[idx] - aux2[idx];
        }
      }
    }
  }
}

// ---------------- MFMA flash attention v8: LDS-staged K/V ----------------
// R6-R10 plateau root cause: direct register fragment loads of K (128B/lane
// stride) and Vt (2KB/lane stride) use 16B of every 64B L2 line -> 3.2 GB
// of line traffic/dispatch -> 93 us at the ~34.5 TB/s L2 ceiling (fits all
// five rounds within 4%). Fix: stage K/Vt tiles cooperatively into LDS with
// full-line coalesced loads (each line fetched once, shared by 4 waves =
// 16x less L2 line traffic), fragments via ds_read_b128 from padded rows
// (stride 72 f16 = 144B: uniform 8 words/bank -> conflict-free, 16B-aligned).
// Staging is software-pipelined: next tile's global loads issue right after
// the barrier, latency hidden under S/exp/PV compute.
#define PSTRIDE 72
#define KVS 72
__global__ __launch_bounds__(256, 3) void flash_attn8(
    const f16* __restrict__ Qg, const f16* __restrict__ Kg,
    const f16* __restrict__ Vt, f16* __restrict__ attn) {
  __shared__ __align__(16) f16 Ks[64 * KVS];
  __shared__ __align__(16) f16 Vs[64 * KVS];
  __shared__ __align__(16) f16 Plds[4][16 * PSTRIDE];
  int tid = threadIdx.x;
  int wv = tid >> 6, lane = tid & 63;
  int bh = blockIdx.x;  // bh fastest: 16 blocks sharing K/V land on one XCD
  int bb = bh / NHEAD, h = bh % NHEAD;
  int m0 = (blockIdx.y * 4 + wv) * 16;
  int am = lane & 15;
  int quad = lane >> 4;
  int ak = quad * 8;

  // staging: 256 threads x 16B cover 32 rows x 64 cols per chunk; 2 chunks
  int srow = tid >> 3;        // 0..31
  int scol = (tid & 7) * 8;   // 0,8,..,56

  const f16* kb = Kg + (((size_t)bh * TSEQ) << 6);
  const f16* vb = Vt + (((size_t)bh * DH) << 10);

  const f16* qbase = Qg + (((size_t)bh * TSEQ + m0) << 6);
  f16x8 qf0 = *(const f16x8*)(qbase + am * 64 + ak);
  f16x8 qf1 = *(const f16x8*)(qbase + am * 64 + 32 + ak);
#pragma unroll
  for (int i = 0; i < 8; i++) { qf0[i] *= (f16)0.125f; qf1[i] *= (f16)0.125f; }

  f16* Pw = Plds[wv];
  f32x4 Oa[4];
#pragma unroll
  for (int i = 0; i < 4; i++) Oa[i] = (f32x4){0.f, 0.f, 0.f, 0.f};
  float lpart[4] = {0.f, 0.f, 0.f, 0.f};

  // prefetch tile 0 staging registers (coalesced full-line loads)
  f16x8 kr0 = *(const f16x8*)(kb + (size_t)srow * 64 + scol);
  f16x8 kr1 = *(const f16x8*)(kb + (size_t)(32 + srow) * 64 + scol);
  f16x8 vr0 = *(const f16x8*)(vb + (size_t)srow * TSEQ + scol);
  f16x8 vr1 = *(const f16x8*)(vb + (size_t)(32 + srow) * TSEQ + scol);

  for (int n0 = 0; n0 < TSEQ; n0 += 64) {
    __syncthreads();  // prior iteration done reading Ks/Vs
    *(f16x8*)&Ks[srow * KVS + scol] = kr0;
    *(f16x8*)&Ks[(32 + srow) * KVS + scol] = kr1;
    *(f16x8*)&Vs[srow * KVS + scol] = vr0;
    *(f16x8*)&Vs[(32 + srow) * KVS + scol] = vr1;
    __syncthreads();
    // issue next tile's global loads now; latency hides under compute
    int nn = n0 + 64;
    if (nn < TSEQ) {
      kr0 = *(const f16x8*)(kb + (size_t)(nn + srow) * 64 + scol);
      kr1 = *(const f16x8*)(kb + (size_t)(nn + 32 + srow) * 64 + scol);
      vr0 = *(const f16x8*)(vb + (size_t)srow * TSEQ + nn + scol);
      vr1 = *(const f16x8*)(vb + (size_t)(32 + srow) * TSEQ + nn + scol);
    }
    // ---- S = Q K^T (K frags from LDS) ----
    f32x4 S[4];
#pragma unroll
    for (int t = 0; t < 4; t++) {
      f16x8 kf0 = *(const f16x8*)&Ks[(16 * t + am) * KVS + ak];
      f16x8 kf1 = *(const f16x8*)&Ks[(16 * t + am) * KVS + 32 + ak];
      S[t] = __builtin_amdgcn_mfma_f32_16x16x32_f16(
          qf0, kf0, (f32x4){0.f, 0.f, 0.f, 0.f}, 0, 0, 0);
      S[t] = __builtin_amdgcn_mfma_f32_16x16x32_f16(qf1, kf1, S[t], 0, 0, 0);
    }
    // ---- p = exp(s) (fixed shift), accumulate l, stage P to LDS ----
#pragma unroll
    for (int t = 0; t < 4; t++) {
#pragma unroll
      for (int r = 0; r < 4; r++) {
        float p = __expf(S[t][r]);
        lpart[r] += p;
        Pw[(quad * 4 + r) * PSTRIDE + 16 * t + am] = (f16)p;
      }
    }
    // ---- P (A-layout from LDS) @ V (B-frags from LDS Vt tile) ----
    f16x8 pa0 = *(const f16x8*)&Pw[am * PSTRIDE + ak];
    f16x8 pa1 = *(const f16x8*)&Pw[am * PSTRIDE + 32 + ak];
#pragma unroll
    for (int dt = 0; dt < 4; dt++) {
      f16x8 vf0 = *(const f16x8*)&Vs[(16 * dt + am) * KVS + ak];
      f16x8 vf1 = *(const f16x8*)&Vs[(16 * dt + am) * KVS + 32 + ak];
      Oa[dt] = __builtin_amdgcn_mfma_f32_16x16x32_f16(pa0, vf0, Oa[dt], 0, 0, 0);
      Oa[dt] = __builtin_amdgcn_mfma_f32_16x16x32_f16(pa1, vf1, Oa[dt], 0, 0, 0);
    }
  }

  // ---- single final l reduction across the 16 lanes of each quad-row ----
#pragma unroll
  for (int o = 1; o < 16; o <<= 1)
#pragma unroll
    for (int r = 0; r < 4; r++) lpart[r] += __shfl_xor(lpart[r], o, 64);

  // ---- epilogue: O[m][d] / l -> attn (f16 [B,T,C] at col h*64+d) ----
#pragma unroll
  for (int r = 0; r < 4; r++) {
    int m = m0 + quad * 4 + r;
    float inv = 1.f / lpart[r];
    f16* orow = attn + ((size_t)(bb * TSEQ + m)) * CDIM + h * DH;
#pragma unroll
    for (int dt = 0; dt < 4; dt++)
      orow[dt * 16 + am] = (f16)(Oa[dt][r] * inv);
  }
}

// ---------------- Anderson: first iteration (K=0): z += res --------------
__global__ __launch_bounds__(256) void add_res_kernel(
    float* __restrict__ z, const float* __restrict__ r) {
  size_t i = (size_t)blockIdx.x * 256 + threadIdx.x;
  z[i] += r[i];
}

// ---------------- Anderson update, K previous residuals, per-token LS -----
template <int KA>
__global__ __launch_bounds__(256) void anderson_kernel(
    float* __restrict__ z, const float* __restrict__ rescur,
    const float* __restrict__ p0, const float* __restrict__ p1,
    const float* __restrict__ p2, const float* __restrict__ p3) {
  __shared__ float sbuf[4];
  int row = blockIdx.x, tid = threadIdx.x;
  size_t base = (size_t)row * CDIM + tid;
  float r[3];
#pragma unroll
  for (int i = 0; i < 3; i++) r[i] = rescur[base + i * 256];
  const float* ps[4] = {p0, p1, p2, p3};
  float dF[KA][3];
#pragma unroll
  for (int k = 0; k < KA; k++)
#pragma unroll
    for (int i = 0; i < 3; i++) dF[k][i] = ps[k][base + i * 256] - r[i];

  float Gm[KA][KA], bv[KA];
#pragma unroll
  for (int k = 0; k < KA; k++) {
#pragma unroll
    for (int ll = k; ll < KA; ll++) {
      float p = 0.f;
#pragma unroll
      for (int i = 0; i < 3; i++) p += dF[k][i] * dF[ll][i];
      float t = block_reduce_sum(p, sbuf);
      Gm[k][ll] = t;
      Gm[ll][k] = t;
    }
  }
#pragma unroll
  for (int k = 0; k < KA; k++) Gm[k][k] += 1e-6f;
#pragma unroll
  for (int k = 0; k < KA; k++) {
    float p = 0.f;
#pragma unroll
    for (int i = 0; i < 3; i++) p += dF[k][i] * r[i];
    bv[k] = block_reduce_sum(p, sbuf);
  }
  float alpha[KA];
#pragma unroll
  for (int p = 0; p < KA; p++) {
    float inv = 1.f / Gm[p][p];
#pragma unroll
    for (int rr = p + 1; rr < KA; rr++) {
      float f = Gm[rr][p] * inv;
#pragma unroll
      for (int c = p; c < KA; c++) Gm[rr][c] -= f * Gm[p][c];
      bv[rr] -= f * bv[p];
    }
  }
#pragma unroll
  for (int p = KA - 1; p >= 0; p--) {
    float s2 = bv[p];
#pragma unroll
    for (int c = p + 1; c < KA; c++) s2 -= Gm[p][c] * alpha[c];
    alpha[p] = s2 / Gm[p][p];
  }
#pragma unroll
  for (int i = 0; i < 3; i++) {
    float d = r[i];
#pragma unroll
    for (int k = 0; k < KA; k++) d = fmaf(-dF[k][i], alpha[k], d);
    z[base + i * 256] += d;
  }
}

extern "C" void kernel_launch(void* const* d_in, const int* in_sizes, int n_in,
                              void* d_out, int out_size, void* d_ws,
                              size_t ws_size, hipStream_t stream) {
  (void)in_sizes; (void)n_in; (void)out_size; (void)ws_size;
  const float* u = (const float*)d_in[0];
  const float* iter_emb = (const float*)d_in[1];
  const float* ln1w = (const float*)d_in[2];
  const float* ln1b = (const float*)d_in[3];
  const float* wqkv = (const float*)d_in[4];
  const float* bqkv = (const float*)d_in[5];
  const float* wo = (const float*)d_in[6];
  const float* bo = (const float*)d_in[7];
  const float* ln2w = (const float*)d_in[8];
  const float* ln2b = (const float*)d_in[9];
  const float* w1 = (const float*)d_in[10];
  const float* b1 = (const float*)d_in[11];
  const float* w2 = (const float*)d_in[12];
  const float* b2 = (const float*)d_in[13];

  const size_t S = (size_t)BT * CDIM;  // 3,145,728
  float* ws = (float*)d_ws;
  // fp32 slots:
  float* z = ws + 0 * S;
  float* zattn = ws + 1 * S;
  float* res[5] = {ws + 2 * S, ws + 3 * S, ws + 4 * S, ws + 5 * S, ws + 6 * S};
  // f16 region:
  f16* q_h = (f16*)(ws + 7 * S);   // S f16: [7.0,7.5)   [B,H,T,64]
  f16* k_h = q_h + S;              // [7.5,8.0)          [B,H,T,64]
  f16* vt_h = q_h + 2 * S;         // [8.0,8.5)          [B,H,64,T]
  f16* h_h = (f16*)(ws + 7 * S);   // 4S f16 [7.0,9.0) — aliases q/k/vt
                                   // (disjoint lifetime: mlp1..mlp2 only)
  f16* x_h = (f16*)(ws + 9 * S);   // S f16 [9.0,9.5): LN out / attn out
  f16* wqkv_h = x_h + S;
  f16* wo_h = wqkv_h + (size_t)3 * CDIM * CDIM;
  f16* w1_h = wo_h + (size_t)CDIM * CDIM;
  f16* w2_h = w1_h + (size_t)4 * CDIM * CDIM;

  cvt_f16_kernel<<<1728, 256, 0, stream>>>(wqkv, wqkv_h);
  cvt_f16_kernel<<<576, 256, 0, stream>>>(wo, wo_h);
  cvt_f16_kernel<<<2304, 256, 0, stream>>>(w1, w1_h);
  cvt_f16_kernel<<<2304, 256, 0, stream>>>(w2, w2_h);
  zero_kernel<<<S / 1024, 256, 0, stream>>>((float4*)z);

  for (int it = 0; it < 6; it++) {
    ln1_kernel<<<BT, 256, 0, stream>>>(z, u, iter_emb + it * CDIM, ln1w, ln1b,
                                       x_h);
    gemm_mfma<3><<<dim3(18, 32), 256, 0, stream>>>(
        x_h, wqkv_h, bqkv, q_h, k_h, vt_h, nullptr, BT, 3 * CDIM, CDIM);
    flash_attn8<<<dim3(BBATCH * NHEAD, TSEQ / 64), 256, 0, stream>>>(
        q_h, k_h, vt_h, x_h);
    gemm_mfma64<0><<<dim3(12, 64), 256, 0, stream>>>(
        x_h, wo_h, bo, z, nullptr, zattn, BT, CDIM, CDIM);
    ln2_kernel<<<BT, 256, 0, stream>>>(zattn, ln2w, ln2b, x_h);
    gemm_mfma<1><<<dim3(24, 32), 256, 0, stream>>>(
        x_h, w1_h, b1, nullptr, nullptr, nullptr, h_h, BT, 4 * CDIM, CDIM);
    float* rcur = res[it % 5];
    gemm_mfma64<2><<<dim3(12, 64), 256, 0, stream>>>(
        h_h, w2_h, b2, zattn, z, rcur, BT, CDIM, 4 * CDIM);

    int Kh = it < 4 ? it : 4;
    if (Kh == 0) {
      add_res_kernel<<<S / 256, 256, 0, stream>>>(z, rcur);
    } else {
      const float* p[4] = {rcur, rcur, rcur, rcur};
      for (int kx = 1; kx <= Kh; kx++) p[kx - 1] = res[(it - kx) % 5];
      switch (Kh) {
        case 1: anderson_kernel<1><<<BT, 256, 0, stream>>>(z, rcur, p[0], p[1], p[2], p[3]); break;
        case 2: anderson_kernel<2><<<BT, 256, 0, stream>>>(z, rcur, p[0], p[1], p[2], p[3]); break;
        case 3: anderson_kernel<3><<<BT, 256, 0, stream>>>(z, rcur, p[0], p[1], p[2], p[3]); break;
        default: anderson_kernel<4><<<BT, 256, 0, stream>>>(z, rcur, p[0], p[1], p[2], p[3]); break;
      }
    }
  }
  hipMemcpyAsync(d_out, z, S * sizeof(float), hipMemcpyDeviceToDevice, stream);
}

// Round 12
// 1243.324 us; speedup vs baseline: 1.4485x; 1.1048x over previous
//
#include <hip/hip_runtime.h>
#include <math.h>

#define BT 4096
#define CDIM 768
#define NHEAD 12
#define DH 64
#define TSEQ 1024
#define BBATCH 4

typedef _Float16 f16;
typedef __attribute__((ext_vector_type(4))) _Float16 f16x4;
typedef __attribute__((ext_vector_type(8))) _Float16 f16x8;
typedef __attribute__((ext_vector_type(4))) float f32x4;

__device__ __forceinline__ void gload_lds16(const f16* g, f16* l) {
  __builtin_amdgcn_global_load_lds(
      (const __attribute__((address_space(1))) unsigned*)(const void*)g,
      (__attribute__((address_space(3))) unsigned*)(void*)l, 16, 0, 0);
}

// ---------------- block reduction (256 threads = 4 waves) ----------------
__device__ __forceinline__ float block_reduce_sum(float v, float* sbuf) {
#pragma unroll
  for (int o = 32; o > 0; o >>= 1) v += __shfl_down(v, o, 64);
  int lane = threadIdx.x & 63;
  int w = threadIdx.x >> 6;
  if (lane == 0) sbuf[w] = v;
  __syncthreads();
  float r = sbuf[0] + sbuf[1] + sbuf[2] + sbuf[3];
  __syncthreads();
  return r;
}

// ---------------- zero-fill ----------------------------------------------
__global__ __launch_bounds__(256) void zero_kernel(float4* __restrict__ p) {
  p[(size_t)blockIdx.x * 256 + threadIdx.x] = make_float4(0.f, 0.f, 0.f, 0.f);
}

// ---------------- fp32 -> fp16 weight conversion (4 elems/thread) --------
__global__ __launch_bounds__(256) void cvt_f16_kernel(
    const float* __restrict__ in, f16* __restrict__ out) {
  size_t i = ((size_t)blockIdx.x * 256 + threadIdx.x) * 4;
  float4 v = *(const float4*)(in + i);
  f16x4 o = {(f16)v.x, (f16)v.y, (f16)v.z, (f16)v.w};
  *(f16x4*)(out + i) = o;
}

// ---------------- LN1: x_h = f16(LN(z + 0.1*emb + u) * w + b) ------------
__global__ __launch_bounds__(256) void ln1_kernel(
    const float* __restrict__ z, const float* __restrict__ u,
    const float* __restrict__ emb, const float* __restrict__ w,
    const float* __restrict__ b, f16* __restrict__ x) {
  __shared__ float sbuf[4];
  int row = blockIdx.x;
  int tid = threadIdx.x;
  const float* zr = z + (size_t)row * CDIM;
  const float* ur = u + (size_t)row * CDIM;
  float v[3];
  float s = 0.f;
#pragma unroll
  for (int i = 0; i < 3; i++) {
    int c = tid + i * 256;
    v[i] = zr[c] + 0.1f * emb[c] + ur[c];
    s += v[i];
  }
  s = block_reduce_sum(s, sbuf);
  float mu = s * (1.f / CDIM);
  float sq = 0.f;
#pragma unroll
  for (int i = 0; i < 3; i++) { v[i] -= mu; sq += v[i] * v[i]; }
  sq = block_reduce_sum(sq, sbuf);
  float rstd = rsqrtf(sq * (1.f / CDIM) + 1e-5f);
  f16* xr = x + (size_t)row * CDIM;
#pragma unroll
  for (int i = 0; i < 3; i++) {
    int c = tid + i * 256;
    xr[c] = (f16)(v[i] * rstd * w[c] + b[c]);
  }
}

// ---------------- LN2 ----------------------------------------------------
__global__ __launch_bounds__(256) void ln2_kernel(
    const float* __restrict__ in, const float* __restrict__ w,
    const float* __restrict__ b, f16* __restrict__ x) {
  __shared__ float sbuf[4];
  int row = blockIdx.x;
  int tid = threadIdx.x;
  const float* ir = in + (size_t)row * CDIM;
  float v[3];
  float s = 0.f;
#pragma unroll
  for (int i = 0; i < 3; i++) {
    int c = tid + i * 256;
    v[i] = ir[c];
    s += v[i];
  }
  s = block_reduce_sum(s, sbuf);
  float mu = s * (1.f / CDIM);
  float sq = 0.f;
#pragma unroll
  for (int i = 0; i < 3; i++) { v[i] -= mu; sq += v[i] * v[i]; }
  sq = block_reduce_sum(sq, sbuf);
  float rstd = rsqrtf(sq * (1.f / CDIM) + 1e-5f);
  f16* xr = x + (size_t)row * CDIM;
#pragma unroll
  for (int i = 0; i < 3; i++) {
    int c = tid + i * 256;
    xr[c] = (f16)(v[i] * rstd * w[c] + b[c]);
  }
}

__device__ __forceinline__ float gelu_exact(float t) {
  return 0.5f * t * (1.f + erff(t * 0.70710678118654752f));
}

// ---------------- fp16 MFMA GEMM 128x128 (m97 structure) -----------------
// MODE 1: hout  = f16(gelu(acc + bias))            (mlp1)
// MODE 3: scatter f16 q/k to [B,H,T,64], v transposed to [B,H,64,T]
template <int MODE>
__global__ __launch_bounds__(256, 3) void gemm_mfma(
    const f16* __restrict__ A, const f16* __restrict__ W,
    const float* __restrict__ bias, f16* __restrict__ hq,
    f16* __restrict__ hk, f16* __restrict__ hvt, f16* __restrict__ hout,
    int M, int N, int K) {
  __shared__ __align__(16) f16 As[128 * 32];
  __shared__ __align__(16) f16 Bs[128 * 32];
  int tid = threadIdx.x;
  int wv = tid >> 6, lane = tid & 63;
  int bm = blockIdx.y, bn = blockIdx.x;
  int wm = (wv >> 1) * 64, wn = (wv & 1) * 64;

  int srow = wv * 16 + (lane >> 2);
  int scol = (lane & 3) * 8;
  const f16* gA = A + (size_t)(bm * 128 + srow) * K + scol;
  const f16* gB = W + (size_t)(bn * 128 + srow) * K + scol;
  f16* lA = As + wv * 16 * 32;
  f16* lB = Bs + wv * 16 * 32;

  f32x4 acc[4][4];
#pragma unroll
  for (int i = 0; i < 4; i++)
#pragma unroll
    for (int j = 0; j < 4; j++) acc[i][j] = (f32x4){0.f, 0.f, 0.f, 0.f};

  int arow = lane & 15;
  int koff = (lane >> 4) * 8;

  for (int k0 = 0; k0 < K; k0 += 32) {
    __syncthreads();
    gload_lds16(gA + k0, lA);
    gload_lds16(gA + (size_t)64 * K + k0, lA + 64 * 32);
    gload_lds16(gB + k0, lB);
    gload_lds16(gB + (size_t)64 * K + k0, lB + 64 * 32);
    __syncthreads();
    f16x8 af[4], bfr[4];
#pragma unroll
    for (int mi = 0; mi < 4; mi++)
      af[mi] = *(const f16x8*)&As[(wm + mi * 16 + arow) * 32 + koff];
#pragma unroll
    for (int nj = 0; nj < 4; nj++)
      bfr[nj] = *(const f16x8*)&Bs[(wn + nj * 16 + arow) * 32 + koff];
#pragma unroll
    for (int mi = 0; mi < 4; mi++)
#pragma unroll
      for (int nj = 0; nj < 4; nj++)
        acc[mi][nj] = __builtin_amdgcn_mfma_f32_16x16x32_f16(
            af[mi], bfr[nj], acc[mi][nj], 0, 0, 0);
  }

  // C/D layout: col = lane&15, row = (lane>>4)*4 + reg
  int crow0 = bm * 128 + wm + (lane >> 4) * 4;
  int ccol0 = bn * 128 + wn + (lane & 15);
#pragma unroll
  for (int nj = 0; nj < 4; nj++) {
    int col = ccol0 + nj * 16;
    float bcol = bias[col];
    if constexpr (MODE == 3) {
      int which = col / CDIM;
      int rem = col - which * CDIM;
      int h = rem >> 6;
      int d = rem & 63;
#pragma unroll
      for (int mi = 0; mi < 4; mi++) {
#pragma unroll
        for (int r = 0; r < 4; r++) {
          int m = crow0 + mi * 16 + r;
          int bb = m >> 10, t = m & 1023;
          f16 val = (f16)(acc[mi][nj][r] + bcol);
          if (which == 0)
            hq[(((size_t)(bb * NHEAD + h) * TSEQ + t) << 6) + d] = val;
          else if (which == 1)
            hk[(((size_t)(bb * NHEAD + h) * TSEQ + t) << 6) + d] = val;
          else
            hvt[(((size_t)(bb * NHEAD + h) * DH + d) << 10) + t] = val;
        }
      }
    } else {  // MODE 1
#pragma unroll
      for (int mi = 0; mi < 4; mi++) {
#pragma unroll
        for (int r = 0; r < 4; r++) {
          int m = crow0 + mi * 16 + r;
          size_t idx = (size_t)m * N + col;
          hout[idx] = (f16)gelu_exact(acc[mi][nj][r] + bcol);
        }
      }
    }
  }
}

// ---------------- fp16 MFMA GEMM 64x64 v2 (N=768 GEMMs) ------------------
// R11 counters on v1: 4.7M bank conflicts (row stride 32 f16 -> 8-way on
// every ds_read_b128), 4 MFMAs per barrier-pair, A-tiles re-fetched across
// XCDs (FETCH 120 MB vs ~55 ideal). v2: BK=64 (8 MFMAs/barrier-pair, half
// the barriers), register staging into PADDED LDS rows (stride 72 f16 =
// 144 B -> bank = 4*row mod 32 -> 2-way alias = free; global_load_lds can't
// pad, registers can), software-pipelined staging (flash_attn8 pattern),
// and grid transposed (bm = blockIdx.x) so the 12 blocks sharing an A-tile
// sit 64 apart == 0 mod 8 -> same XCD -> A fetched once per L2.
// MODE 0: fout0 = acc + bias + aux1               (out-proj residual)
// MODE 2: fout0 = acc + bias + aux1 - aux2        (mlp2 -> residual F)
#define GS 72
template <int MODE>
__global__ __launch_bounds__(256, 4) void gemm_mfma64(
    const f16* __restrict__ A, const f16* __restrict__ W,
    const float* __restrict__ bias, const float* __restrict__ aux1,
    const float* __restrict__ aux2, float* __restrict__ fout0,
    int M, int N, int K) {
  __shared__ __align__(16) f16 As[64 * GS];
  __shared__ __align__(16) f16 Bs[64 * GS];
  int tid = threadIdx.x;
  int wv = tid >> 6, lane = tid & 63;
  int bm = blockIdx.x, bn = blockIdx.y;  // transposed for XCD A-reuse
  int wm = (wv >> 1) * 32, wn = (wv & 1) * 32;

  // staging map: 4 lanes x 16B cover one 64B-line row segment
  int srow = tid >> 2;          // 0..63
  int scol = (tid & 3) * 16;    // 0,16,32,48
  const f16* gA = A + (size_t)(bm * 64 + srow) * K + scol;
  const f16* gB = W + (size_t)(bn * 64 + srow) * K + scol;

  f32x4 acc[2][2];
#pragma unroll
  for (int i = 0; i < 2; i++)
#pragma unroll
    for (int j = 0; j < 2; j++) acc[i][j] = (f32x4){0.f, 0.f, 0.f, 0.f};

  int am = lane & 15;
  int ak = (lane >> 4) * 8;

  // prefetch tile 0
  f16x8 a0 = *(const f16x8*)(gA);
  f16x8 a1 = *(const f16x8*)(gA + 8);
  f16x8 b0 = *(const f16x8*)(gB);
  f16x8 b1 = *(const f16x8*)(gB + 8);

  for (int k0 = 0; k0 < K; k0 += 64) {
    __syncthreads();
    *(f16x8*)&As[srow * GS + scol] = a0;
    *(f16x8*)&As[srow * GS + scol + 8] = a1;
    *(f16x8*)&Bs[srow * GS + scol] = b0;
    *(f16x8*)&Bs[srow * GS + scol + 8] = b1;
    __syncthreads();
    int kn = k0 + 64;
    if (kn < K) {  // next tile's loads in flight under compute
      a0 = *(const f16x8*)(gA + kn);
      a1 = *(const f16x8*)(gA + kn + 8);
      b0 = *(const f16x8*)(gB + kn);
      b1 = *(const f16x8*)(gB + kn + 8);
    }
#pragma unroll
    for (int kk = 0; kk < 2; kk++) {
      f16x8 af[2], bfr[2];
#pragma unroll
      for (int mi = 0; mi < 2; mi++)
        af[mi] = *(const f16x8*)&As[(wm + mi * 16 + am) * GS + kk * 32 + ak];
#pragma unroll
      for (int nj = 0; nj < 2; nj++)
        bfr[nj] = *(const f16x8*)&Bs[(wn + nj * 16 + am) * GS + kk * 32 + ak];
#pragma unroll
      for (int mi = 0; mi < 2; mi++)
#pragma unroll
        for (int nj = 0; nj < 2; nj++)
          acc[mi][nj] = __builtin_amdgcn_mfma_f32_16x16x32_f16(
              af[mi], bfr[nj], acc[mi][nj], 0, 0, 0);
    }
  }

  int crow0 = bm * 64 + wm + (lane >> 4) * 4;
  int ccol0 = bn * 64 + wn + (lane & 15);
#pragma unroll
  for (int nj = 0; nj < 2; nj++) {
    int col = ccol0 + nj * 16;
    float bcol = bias[col];
#pragma unroll
    for (int mi = 0; mi < 2; mi++) {
#pragma unroll
      for (int r = 0; r < 4; r++) {
        int m = crow0 + mi * 16 + r;
        size_t idx = (size_t)m * N + col;
        float val = acc[mi][nj][r] + bcol;
        if constexpr (MODE == 0) {
          fout0[idx] = val + aux1[idx];
        } else {  // MODE 2
          fout0[idx] = val + aux1[idx] - aux2[idx];
        }
      }
    }
  }
}

// ---------------- MFMA flash attention v8: LDS-staged K/V ----------------
// (R11-verified: L2 line traffic was the R6-R10 binder; staging killed it.)
#define PSTRIDE 72
#define KVS 72
__global__ __launch_bounds__(256, 3) void flash_attn8(
    const f16* __restrict__ Qg, const f16* __restrict__ Kg,
    const f16* __restrict__ Vt, f16* __restrict__ attn) {
  __shared__ __align__(16) f16 Ks[64 * KVS];
  __shared__ __align__(16) f16 Vs[64 * KVS];
  __shared__ __align__(16) f16 Plds[4][16 * PSTRIDE];
  int tid = threadIdx.x;
  int wv = tid >> 6, lane = tid & 63;
  int bh = blockIdx.x;  // bh fastest: 16 blocks sharing K/V land on one XCD
  int bb = bh / NHEAD, h = bh % NHEAD;
  int m0 = (blockIdx.y * 4 + wv) * 16;
  int am = lane & 15;
  int quad = lane >> 4;
  int ak = quad * 8;

  int srow = tid >> 3;        // 0..31
  int scol = (tid & 7) * 8;   // 0,8,..,56

  const f16* kb = Kg + (((size_t)bh * TSEQ) << 6);
  const f16* vb = Vt + (((size_t)bh * DH) << 10);

  const f16* qbase = Qg + (((size_t)bh * TSEQ + m0) << 6);
  f16x8 qf0 = *(const f16x8*)(qbase + am * 64 + ak);
  f16x8 qf1 = *(const f16x8*)(qbase + am * 64 + 32 + ak);
#pragma unroll
  for (int i = 0; i < 8; i++) { qf0[i] *= (f16)0.125f; qf1[i] *= (f16)0.125f; }

  f16* Pw = Plds[wv];
  f32x4 Oa[4];
#pragma unroll
  for (int i = 0; i < 4; i++) Oa[i] = (f32x4){0.f, 0.f, 0.f, 0.f};
  float lpart[4] = {0.f, 0.f, 0.f, 0.f};

  f16x8 kr0 = *(const f16x8*)(kb + (size_t)srow * 64 + scol);
  f16x8 kr1 = *(const f16x8*)(kb + (size_t)(32 + srow) * 64 + scol);
  f16x8 vr0 = *(const f16x8*)(vb + (size_t)srow * TSEQ + scol);
  f16x8 vr1 = *(const f16x8*)(vb + (size_t)(32 + srow) * TSEQ + scol);

  for (int n0 = 0; n0 < TSEQ; n0 += 64) {
    __syncthreads();
    *(f16x8*)&Ks[srow * KVS + scol] = kr0;
    *(f16x8*)&Ks[(32 + srow) * KVS + scol] = kr1;
    *(f16x8*)&Vs[srow * KVS + scol] = vr0;
    *(f16x8*)&Vs[(32 + srow) * KVS + scol] = vr1;
    __syncthreads();
    int nn = n0 + 64;
    if (nn < TSEQ) {
      kr0 = *(const f16x8*)(kb + (size_t)(nn + srow) * 64 + scol);
      kr1 = *(const f16x8*)(kb + (size_t)(nn + 32 + srow) * 64 + scol);
      vr0 = *(const f16x8*)(vb + (size_t)srow * TSEQ + nn + scol);
      vr1 = *(const f16x8*)(vb + (size_t)(32 + srow) * TSEQ + nn + scol);
    }
    f32x4 S[4];
#pragma unroll
    for (int t = 0; t < 4; t++) {
      f16x8 kf0 = *(const f16x8*)&Ks[(16 * t + am) * KVS + ak];
      f16x8 kf1 = *(const f16x8*)&Ks[(16 * t + am) * KVS + 32 + ak];
      S[t] = __builtin_amdgcn_mfma_f32_16x16x32_f16(
          qf0, kf0, (f32x4){0.f, 0.f, 0.f, 0.f}, 0, 0, 0);
      S[t] = __builtin_amdgcn_mfma_f32_16x16x32_f16(qf1, kf1, S[t], 0, 0, 0);
    }
#pragma unroll
    for (int t = 0; t < 4; t++) {
#pragma unroll
      for (int r = 0; r < 4; r++) {
        float p = __expf(S[t][r]);
        lpart[r] += p;
        Pw[(quad * 4 + r) * PSTRIDE + 16 * t + am] = (f16)p;
      }
    }
    f16x8 pa0 = *(const f16x8*)&Pw[am * PSTRIDE + ak];
    f16x8 pa1 = *(const f16x8*)&Pw[am * PSTRIDE + 32 + ak];
#pragma unroll
    for (int dt = 0; dt < 4; dt++) {
      f16x8 vf0 = *(const f16x8*)&Vs[(16 * dt + am) * KVS + ak];
      f16x8 vf1 = *(const f16x8*)&Vs[(16 * dt + am) * KVS + 32 + ak];
      Oa[dt] = __builtin_amdgcn_mfma_f32_16x16x32_f16(pa0, vf0, Oa[dt], 0, 0, 0);
      Oa[dt] = __builtin_amdgcn_mfma_f32_16x16x32_f16(pa1, vf1, Oa[dt], 0, 0, 0);
    }
  }

#pragma unroll
  for (int o = 1; o < 16; o <<= 1)
#pragma unroll
    for (int r = 0; r < 4; r++) lpart[r] += __shfl_xor(lpart[r], o, 64);

#pragma unroll
  for (int r = 0; r < 4; r++) {
    int m = m0 + quad * 4 + r;
    float inv = 1.f / lpart[r];
    f16* orow = attn + ((size_t)(bb * TSEQ + m)) * CDIM + h * DH;
#pragma unroll
    for (int dt = 0; dt < 4; dt++)
      orow[dt * 16 + am] = (f16)(Oa[dt][r] * inv);
  }
}

// ---------------- Anderson: first iteration (K=0): z += res --------------
__global__ __launch_bounds__(256) void add_res_kernel(
    float* __restrict__ z, const float* __restrict__ r) {
  size_t i = (size_t)blockIdx.x * 256 + threadIdx.x;
  z[i] += r[i];
}

// ---------------- Anderson update, K previous residuals, per-token LS -----
template <int KA>
__global__ __launch_bounds__(256) void anderson_kernel(
    float* __restrict__ z, const float* __restrict__ rescur,
    const float* __restrict__ p0, const float* __restrict__ p1,
    const float* __restrict__ p2, const float* __restrict__ p3) {
  __shared__ float sbuf[4];
  int row = blockIdx.x, tid = threadIdx.x;
  size_t base = (size_t)row * CDIM + tid;
  float r[3];
#pragma unroll
  for (int i = 0; i < 3; i++) r[i] = rescur[base + i * 256];
  const float* ps[4] = {p0, p1, p2, p3};
  float dF[KA][3];
#pragma unroll
  for (int k = 0; k < KA; k++)
#pragma unroll
    for (int i = 0; i < 3; i++) dF[k][i] = ps[k][base + i * 256] - r[i];

  float Gm[KA][KA], bv[KA];
#pragma unroll
  for (int k = 0; k < KA; k++) {
#pragma unroll
    for (int ll = k; ll < KA; ll++) {
      float p = 0.f;
#pragma unroll
      for (int i = 0; i < 3; i++) p += dF[k][i] * dF[ll][i];
      float t = block_reduce_sum(p, sbuf);
      Gm[k][ll] = t;
      Gm[ll][k] = t;
    }
  }
#pragma unroll
  for (int k = 0; k < KA; k++) Gm[k][k] += 1e-6f;
#pragma unroll
  for (int k = 0; k < KA; k++) {
    float p = 0.f;
#pragma unroll
    for (int i = 0; i < 3; i++) p += dF[k][i] * r[i];
    bv[k] = block_reduce_sum(p, sbuf);
  }
  float alpha[KA];
#pragma unroll
  for (int p = 0; p < KA; p++) {
    float inv = 1.f / Gm[p][p];
#pragma unroll
    for (int rr = p + 1; rr < KA; rr++) {
      float f = Gm[rr][p] * inv;
#pragma unroll
      for (int c = p; c < KA; c++) Gm[rr][c] -= f * Gm[p][c];
      bv[rr] -= f * bv[p];
    }
  }
#pragma unroll
  for (int p = KA - 1; p >= 0; p--) {
    float s2 = bv[p];
#pragma unroll
    for (int c = p + 1; c < KA; c++) s2 -= Gm[p][c] * alpha[c];
    alpha[p] = s2 / Gm[p][p];
  }
#pragma unroll
  for (int i = 0; i < 3; i++) {
    float d = r[i];
#pragma unroll
    for (int k = 0; k < KA; k++) d = fmaf(-dF[k][i], alpha[k], d);
    z[base + i * 256] += d;
  }
}

extern "C" void kernel_launch(void* const* d_in, const int* in_sizes, int n_in,
                              void* d_out, int out_size, void* d_ws,
                              size_t ws_size, hipStream_t stream) {
  (void)in_sizes; (void)n_in; (void)out_size; (void)ws_size;
  const float* u = (const float*)d_in[0];
  const float* iter_emb = (const float*)d_in[1];
  const float* ln1w = (const float*)d_in[2];
  const float* ln1b = (const float*)d_in[3];
  const float* wqkv = (const float*)d_in[4];
  const float* bqkv = (const float*)d_in[5];
  const float* wo = (const float*)d_in[6];
  const float* bo = (const float*)d_in[7];
  const float* ln2w = (const float*)d_in[8];
  const float* ln2b = (const float*)d_in[9];
  const float* w1 = (const float*)d_in[10];
  const float* b1 = (const float*)d_in[11];
  const float* w2 = (const float*)d_in[12];
  const float* b2 = (const float*)d_in[13];

  const size_t S = (size_t)BT * CDIM;  // 3,145,728
  float* ws = (float*)d_ws;
  // fp32 slots:
  float* z = ws + 0 * S;
  float* zattn = ws + 1 * S;
  float* res[5] = {ws + 2 * S, ws + 3 * S, ws + 4 * S, ws + 5 * S, ws + 6 * S};
  // f16 region:
  f16* q_h = (f16*)(ws + 7 * S);   // S f16: [7.0,7.5)   [B,H,T,64]
  f16* k_h = q_h + S;              // [7.5,8.0)          [B,H,T,64]
  f16* vt_h = q_h + 2 * S;         // [8.0,8.5)          [B,H,64,T]
  f16* h_h = (f16*)(ws + 7 * S);   // 4S f16 [7.0,9.0) — aliases q/k/vt
                                   // (disjoint lifetime: mlp1..mlp2 only)
  f16* x_h = (f16*)(ws + 9 * S);   // S f16 [9.0,9.5): LN out / attn out
  f16* wqkv_h = x_h + S;
  f16* wo_h = wqkv_h + (size_t)3 * CDIM * CDIM;
  f16* w1_h = wo_h + (size_t)CDIM * CDIM;
  f16* w2_h = w1_h + (size_t)4 * CDIM * CDIM;

  cvt_f16_kernel<<<1728, 256, 0, stream>>>(wqkv, wqkv_h);
  cvt_f16_kernel<<<576, 256, 0, stream>>>(wo, wo_h);
  cvt_f16_kernel<<<2304, 256, 0, stream>>>(w1, w1_h);
  cvt_f16_kernel<<<2304, 256, 0, stream>>>(w2, w2_h);
  zero_kernel<<<S / 1024, 256, 0, stream>>>((float4*)z);

  for (int it = 0; it < 6; it++) {
    ln1_kernel<<<BT, 256, 0, stream>>>(z, u, iter_emb + it * CDIM, ln1w, ln1b,
                                       x_h);
    gemm_mfma<3><<<dim3(18, 32), 256, 0, stream>>>(
        x_h, wqkv_h, bqkv, q_h, k_h, vt_h, nullptr, BT, 3 * CDIM, CDIM);
    flash_attn8<<<dim3(BBATCH * NHEAD, TSEQ / 64), 256, 0, stream>>>(
        q_h, k_h, vt_h, x_h);
    gemm_mfma64<0><<<dim3(64, 12), 256, 0, stream>>>(
        x_h, wo_h, bo, z, nullptr, zattn, BT, CDIM, CDIM);
    ln2_kernel<<<BT, 256, 0, stream>>>(zattn, ln2w, ln2b, x_h);
    gemm_mfma<1><<<dim3(24, 32), 256, 0, stream>>>(
        x_h, w1_h, b1, nullptr, nullptr, nullptr, h_h, BT, 4 * CDIM, CDIM);
    float* rcur = res[it % 5];
    gemm_mfma64<2><<<dim3(64, 12), 256, 0, stream>>>(
        h_h, w2_h, b2, zattn, z, rcur, BT, CDIM, 4 * CDIM);

    int Kh = it < 4 ? it : 4;
    if (Kh == 0) {
      add_res_kernel<<<S / 256, 256, 0, stream>>>(z, rcur);
    } else {
      const float* p[4] = {rcur, rcur, rcur, rcur};
      for (int kx = 1; kx <= Kh; kx++) p[kx - 1] = res[(it - kx) % 5];
      switch (Kh) {
        case 1: anderson_kernel<1><<<BT, 256, 0, stream>>>(z, rcur, p[0], p[1], p[2], p[3]); break;
        case 2: anderson_kernel<2><<<BT, 256, 0, stream>>>(z, rcur, p[0], p[1], p[2], p[3]); break;
        case 3: anderson_kernel<3><<<BT, 256, 0, stream>>>(z, rcur, p[0], p[1], p[2], p[3]); break;
        default: anderson_kernel<4><<<BT, 256, 0, stream>>>(z, rcur, p[0], p[1], p[2], p[3]); break;
      }
    }
  }
  hipMemcpyAsync(d_out, z, S * sizeof(float), hipMemcpyDeviceToDevice, stream);
}

// Round 13
// 1237.565 us; speedup vs baseline: 1.4553x; 1.0047x over previous
//
#include <hip/hip_runtime.h>
#include <math.h>

#define BT 4096
#define CDIM 768
#define NHEAD 12
#define DH 64
#define TSEQ 1024
#define BBATCH 4

typedef _Float16 f16;
typedef __attribute__((ext_vector_type(4))) _Float16 f16x4;
typedef __attribute__((ext_vector_type(8))) _Float16 f16x8;
typedef __attribute__((ext_vector_type(4))) float f32x4;

// ---------------- block reduction (256 threads = 4 waves) ----------------
__device__ __forceinline__ float block_reduce_sum(float v, float* sbuf) {
#pragma unroll
  for (int o = 32; o > 0; o >>= 1) v += __shfl_down(v, o, 64);
  int lane = threadIdx.x & 63;
  int w = threadIdx.x >> 6;
  if (lane == 0) sbuf[w] = v;
  __syncthreads();
  float r = sbuf[0] + sbuf[1] + sbuf[2] + sbuf[3];
  __syncthreads();
  return r;
}

// ---------------- zero-fill ----------------------------------------------
__global__ __launch_bounds__(256) void zero_kernel(float4* __restrict__ p) {
  p[(size_t)blockIdx.x * 256 + threadIdx.x] = make_float4(0.f, 0.f, 0.f, 0.f);
}

// ---------------- fp32 -> fp16 weight conversion (4 elems/thread) --------
__global__ __launch_bounds__(256) void cvt_f16_kernel(
    const float* __restrict__ in, f16* __restrict__ out) {
  size_t i = ((size_t)blockIdx.x * 256 + threadIdx.x) * 4;
  float4 v = *(const float4*)(in + i);
  f16x4 o = {(f16)v.x, (f16)v.y, (f16)v.z, (f16)v.w};
  *(f16x4*)(out + i) = o;
}

// ---------------- LN1: x_h = f16(LN(z + 0.1*emb + u) * w + b) ------------
__global__ __launch_bounds__(256) void ln1_kernel(
    const float* __restrict__ z, const float* __restrict__ u,
    const float* __restrict__ emb, const float* __restrict__ w,
    const float* __restrict__ b, f16* __restrict__ x) {
  __shared__ float sbuf[4];
  int row = blockIdx.x;
  int tid = threadIdx.x;
  const float* zr = z + (size_t)row * CDIM;
  const float* ur = u + (size_t)row * CDIM;
  float v[3];
  float s = 0.f;
#pragma unroll
  for (int i = 0; i < 3; i++) {
    int c = tid + i * 256;
    v[i] = zr[c] + 0.1f * emb[c] + ur[c];
    s += v[i];
  }
  s = block_reduce_sum(s, sbuf);
  float mu = s * (1.f / CDIM);
  float sq = 0.f;
#pragma unroll
  for (int i = 0; i < 3; i++) { v[i] -= mu; sq += v[i] * v[i]; }
  sq = block_reduce_sum(sq, sbuf);
  float rstd = rsqrtf(sq * (1.f / CDIM) + 1e-5f);
  f16* xr = x + (size_t)row * CDIM;
#pragma unroll
  for (int i = 0; i < 3; i++) {
    int c = tid + i * 256;
    xr[c] = (f16)(v[i] * rstd * w[c] + b[c]);
  }
}

// ---------------- LN2 ----------------------------------------------------
__global__ __launch_bounds__(256) void ln2_kernel(
    const float* __restrict__ in, const float* __restrict__ w,
    const float* __restrict__ b, f16* __restrict__ x) {
  __shared__ float sbuf[4];
  int row = blockIdx.x;
  int tid = threadIdx.x;
  const float* ir = in + (size_t)row * CDIM;
  float v[3];
  float s = 0.f;
#pragma unroll
  for (int i = 0; i < 3; i++) {
    int c = tid + i * 256;
    v[i] = ir[c];
    s += v[i];
  }
  s = block_reduce_sum(s, sbuf);
  float mu = s * (1.f / CDIM);
  float sq = 0.f;
#pragma unroll
  for (int i = 0; i < 3; i++) { v[i] -= mu; sq += v[i] * v[i]; }
  sq = block_reduce_sum(sq, sbuf);
  float rstd = rsqrtf(sq * (1.f / CDIM) + 1e-5f);
  f16* xr = x + (size_t)row * CDIM;
#pragma unroll
  for (int i = 0; i < 3; i++) {
    int c = tid + i * 256;
    xr[c] = (f16)(v[i] * rstd * w[c] + b[c]);
  }
}

__device__ __forceinline__ float gelu_exact(float t) {
  return 0.5f * t * (1.f + erff(t * 0.70710678118654752f));
}

// ---------------- fp16 MFMA GEMM 128x128 v2 ------------------------------
// R12 counters on v1 (global_load_lds staging): 2.36M bank conflicts —
// stride-32 rows make every ds_read_b128 8-way (bank = 16*row mod 32).
// global_load_lds's wave-uniform dest can't be padded (m104), so v2 stages
// via registers into PADDED rows (stride 72 f16 -> bank = 4*row mod 32 ->
// 2-way = free), BK=64 (32 MFMAs per barrier-pair, 12 K-iters at K=768),
// software-pipelined prefetch. Same recipe that fixed gemm_mfma64 in R12.
// MODE 1: hout  = f16(gelu(acc + bias))            (mlp1)
// MODE 3: scatter f16 q/k to [B,H,T,64], v transposed to [B,H,64,T]
#define GS128 72
template <int MODE>
__global__ __launch_bounds__(256, 3) void gemm_mfma(
    const f16* __restrict__ A, const f16* __restrict__ W,
    const float* __restrict__ bias, f16* __restrict__ hq,
    f16* __restrict__ hk, f16* __restrict__ hvt, f16* __restrict__ hout,
    int M, int N, int K) {
  __shared__ __align__(16) f16 As[128 * GS128];  // 18.4 KB
  __shared__ __align__(16) f16 Bs[128 * GS128];  // 18.4 KB
  int tid = threadIdx.x;
  int wv = tid >> 6, lane = tid & 63;
  int bm = blockIdx.y, bn = blockIdx.x;
  int wm = (wv >> 1) * 64, wn = (wv & 1) * 64;

  // staging map: 8 lanes x 16B cover one 128B row of the 128x64 K-tile
  int srow = tid >> 3;        // 0..31 (4 chunks of 32 rows)
  int scol = (tid & 7) * 8;   // 0,8,..,56
  const f16* gA = A + (size_t)(bm * 128 + srow) * K + scol;
  const f16* gB = W + (size_t)(bn * 128 + srow) * K + scol;

  f32x4 acc[4][4];
#pragma unroll
  for (int i = 0; i < 4; i++)
#pragma unroll
    for (int j = 0; j < 4; j++) acc[i][j] = (f32x4){0.f, 0.f, 0.f, 0.f};

  int am = lane & 15;
  int quad = lane >> 4;
  int ak = quad * 8;

  // prefetch K-tile 0
  f16x8 ar[4], br[4];
#pragma unroll
  for (int c = 0; c < 4; c++) {
    ar[c] = *(const f16x8*)(gA + (size_t)(c * 32) * K);
    br[c] = *(const f16x8*)(gB + (size_t)(c * 32) * K);
  }

  for (int k0 = 0; k0 < K; k0 += 64) {
    __syncthreads();
#pragma unroll
    for (int c = 0; c < 4; c++) {
      *(f16x8*)&As[(srow + c * 32) * GS128 + scol] = ar[c];
      *(f16x8*)&Bs[(srow + c * 32) * GS128 + scol] = br[c];
    }
    __syncthreads();
    int kn = k0 + 64;
    if (kn < K) {  // next tile's loads in flight under compute
#pragma unroll
      for (int c = 0; c < 4; c++) {
        ar[c] = *(const f16x8*)(gA + (size_t)(c * 32) * K + kn);
        br[c] = *(const f16x8*)(gB + (size_t)(c * 32) * K + kn);
      }
    }
#pragma unroll
    for (int kk = 0; kk < 2; kk++) {
      f16x8 af[4], bfr[4];
#pragma unroll
      for (int mi = 0; mi < 4; mi++)
        af[mi] = *(const f16x8*)&As[(wm + mi * 16 + am) * GS128 + kk * 32 + ak];
#pragma unroll
      for (int nj = 0; nj < 4; nj++)
        bfr[nj] = *(const f16x8*)&Bs[(wn + nj * 16 + am) * GS128 + kk * 32 + ak];
#pragma unroll
      for (int mi = 0; mi < 4; mi++)
#pragma unroll
        for (int nj = 0; nj < 4; nj++)
          acc[mi][nj] = __builtin_amdgcn_mfma_f32_16x16x32_f16(
              af[mi], bfr[nj], acc[mi][nj], 0, 0, 0);
    }
  }

  // C/D layout: col = lane&15, row = quad*4 + reg
  int crow0 = bm * 128 + wm + quad * 4;
  int ccol0 = bn * 128 + wn + am;
#pragma unroll
  for (int nj = 0; nj < 4; nj++) {
    int col = ccol0 + nj * 16;
    float bcol = bias[col];
    if constexpr (MODE == 3) {
      int which = col / CDIM;
      int rem = col - which * CDIM;
      int h = rem >> 6;
      int d = rem & 63;
#pragma unroll
      for (int mi = 0; mi < 4; mi++) {
#pragma unroll
        for (int r = 0; r < 4; r++) {
          int m = crow0 + mi * 16 + r;
          int bb = m >> 10, t = m & 1023;
          f16 val = (f16)(acc[mi][nj][r] + bcol);
          if (which == 0)
            hq[(((size_t)(bb * NHEAD + h) * TSEQ + t) << 6) + d] = val;
          else if (which == 1)
            hk[(((size_t)(bb * NHEAD + h) * TSEQ + t) << 6) + d] = val;
          else
            hvt[(((size_t)(bb * NHEAD + h) * DH + d) << 10) + t] = val;
        }
      }
    } else {  // MODE 1
#pragma unroll
      for (int mi = 0; mi < 4; mi++) {
#pragma unroll
        for (int r = 0; r < 4; r++) {
          int m = crow0 + mi * 16 + r;
          size_t idx = (size_t)m * N + col;
          hout[idx] = (f16)gelu_exact(acc[mi][nj][r] + bcol);
        }
      }
    }
  }
}

// ---------------- fp16 MFMA GEMM 64x64 v2 (N=768 GEMMs) ------------------
// MODE 0: fout0 = acc + bias + aux1               (out-proj residual)
// MODE 2: fout0 = acc + bias + aux1 - aux2        (mlp2 -> residual F)
#define GS 72
template <int MODE>
__global__ __launch_bounds__(256, 4) void gemm_mfma64(
    const f16* __restrict__ A, const f16* __restrict__ W,
    const float* __restrict__ bias, const float* __restrict__ aux1,
    const float* __restrict__ aux2, float* __restrict__ fout0,
    int M, int N, int K) {
  __shared__ __align__(16) f16 As[64 * GS];
  __shared__ __align__(16) f16 Bs[64 * GS];
  int tid = threadIdx.x;
  int wv = tid >> 6, lane = tid & 63;
  int bm = blockIdx.x, bn = blockIdx.y;  // transposed for XCD A-reuse
  int wm = (wv >> 1) * 32, wn = (wv & 1) * 32;

  int srow = tid >> 2;          // 0..63
  int scol = (tid & 3) * 16;    // 0,16,32,48
  const f16* gA = A + (size_t)(bm * 64 + srow) * K + scol;
  const f16* gB = W + (size_t)(bn * 64 + srow) * K + scol;

  f32x4 acc[2][2];
#pragma unroll
  for (int i = 0; i < 2; i++)
#pragma unroll
    for (int j = 0; j < 2; j++) acc[i][j] = (f32x4){0.f, 0.f, 0.f, 0.f};

  int am = lane & 15;
  int ak = (lane >> 4) * 8;

  f16x8 a0 = *(const f16x8*)(gA);
  f16x8 a1 = *(const f16x8*)(gA + 8);
  f16x8 b0 = *(const f16x8*)(gB);
  f16x8 b1 = *(const f16x8*)(gB + 8);

  for (int k0 = 0; k0 < K; k0 += 64) {
    __syncthreads();
    *(f16x8*)&As[srow * GS + scol] = a0;
    *(f16x8*)&As[srow * GS + scol + 8] = a1;
    *(f16x8*)&Bs[srow * GS + scol] = b0;
    *(f16x8*)&Bs[srow * GS + scol + 8] = b1;
    __syncthreads();
    int kn = k0 + 64;
    if (kn < K) {
      a0 = *(const f16x8*)(gA + kn);
      a1 = *(const f16x8*)(gA + kn + 8);
      b0 = *(const f16x8*)(gB + kn);
      b1 = *(const f16x8*)(gB + kn + 8);
    }
#pragma unroll
    for (int kk = 0; kk < 2; kk++) {
      f16x8 af[2], bfr[2];
#pragma unroll
      for (int mi = 0; mi < 2; mi++)
        af[mi] = *(const f16x8*)&As[(wm + mi * 16 + am) * GS + kk * 32 + ak];
#pragma unroll
      for (int nj = 0; nj < 2; nj++)
        bfr[nj] = *(const f16x8*)&Bs[(wn + nj * 16 + am) * GS + kk * 32 + ak];
#pragma unroll
      for (int mi = 0; mi < 2; mi++)
#pragma unroll
        for (int nj = 0; nj < 2; nj++)
          acc[mi][nj] = __builtin_amdgcn_mfma_f32_16x16x32_f16(
              af[mi], bfr[nj], acc[mi][nj], 0, 0, 0);
    }
  }

  int crow0 = bm * 64 + wm + (lane >> 4) * 4;
  int ccol0 = bn * 64 + wn + (lane & 15);
#pragma unroll
  for (int nj = 0; nj < 2; nj++) {
    int col = ccol0 + nj * 16;
    float bcol = bias[col];
#pragma unroll
    for (int mi = 0; mi < 2; mi++) {
#pragma unroll
      for (int r = 0; r < 4; r++) {
        int m = crow0 + mi * 16 + r;
        size_t idx = (size_t)m * N + col;
        float val = acc[mi][nj][r] + bcol;
        if constexpr (MODE == 0) {
          fout0[idx] = val + aux1[idx];
        } else {  // MODE 2
          fout0[idx] = val + aux1[idx] - aux2[idx];
        }
      }
    }
  }
}

// ---------------- MFMA flash attention v8: LDS-staged K/V ----------------
// (R11-verified: L2 line traffic was the R6-R10 binder; staging killed it.)
#define PSTRIDE 72
#define KVS 72
__global__ __launch_bounds__(256, 3) void flash_attn8(
    const f16* __restrict__ Qg, const f16* __restrict__ Kg,
    const f16* __restrict__ Vt, f16* __restrict__ attn) {
  __shared__ __align__(16) f16 Ks[64 * KVS];
  __shared__ __align__(16) f16 Vs[64 * KVS];
  __shared__ __align__(16) f16 Plds[4][16 * PSTRIDE];
  int tid = threadIdx.x;
  int wv = tid >> 6, lane = tid & 63;
  int bh = blockIdx.x;  // bh fastest: 16 blocks sharing K/V land on one XCD
  int bb = bh / NHEAD, h = bh % NHEAD;
  int m0 = (blockIdx.y * 4 + wv) * 16;
  int am = lane & 15;
  int quad = lane >> 4;
  int ak = quad * 8;

  int srow = tid >> 3;        // 0..31
  int scol = (tid & 7) * 8;   // 0,8,..,56

  const f16* kb = Kg + (((size_t)bh * TSEQ) << 6);
  const f16* vb = Vt + (((size_t)bh * DH) << 10);

  const f16* qbase = Qg + (((size_t)bh * TSEQ + m0) << 6);
  f16x8 qf0 = *(const f16x8*)(qbase + am * 64 + ak);
  f16x8 qf1 = *(const f16x8*)(qbase + am * 64 + 32 + ak);
#pragma unroll
  for (int i = 0; i < 8; i++) { qf0[i] *= (f16)0.125f; qf1[i] *= (f16)0.125f; }

  f16* Pw = Plds[wv];
  f32x4 Oa[4];
#pragma unroll
  for (int i = 0; i < 4; i++) Oa[i] = (f32x4){0.f, 0.f, 0.f, 0.f};
  float lpart[4] = {0.f, 0.f, 0.f, 0.f};

  f16x8 kr0 = *(const f16x8*)(kb + (size_t)srow * 64 + scol);
  f16x8 kr1 = *(const f16x8*)(kb + (size_t)(32 + srow) * 64 + scol);
  f16x8 vr0 = *(const f16x8*)(vb + (size_t)srow * TSEQ + scol);
  f16x8 vr1 = *(const f16x8*)(vb + (size_t)(32 + srow) * TSEQ + scol);

  for (int n0 = 0; n0 < TSEQ; n0 += 64) {
    __syncthreads();
    *(f16x8*)&Ks[srow * KVS + scol] = kr0;
    *(f16x8*)&Ks[(32 + srow) * KVS + scol] = kr1;
    *(f16x8*)&Vs[srow * KVS + scol] = vr0;
    *(f16x8*)&Vs[(32 + srow) * KVS + scol] = vr1;
    __syncthreads();
    int nn = n0 + 64;
    if (nn < TSEQ) {
      kr0 = *(const f16x8*)(kb + (size_t)(nn + srow) * 64 + scol);
      kr1 = *(const f16x8*)(kb + (size_t)(nn + 32 + srow) * 64 + scol);
      vr0 = *(const f16x8*)(vb + (size_t)srow * TSEQ + nn + scol);
      vr1 = *(const f16x8*)(vb + (size_t)(32 + srow) * TSEQ + nn + scol);
    }
    f32x4 S[4];
#pragma unroll
    for (int t = 0; t < 4; t++) {
      f16x8 kf0 = *(const f16x8*)&Ks[(16 * t + am) * KVS + ak];
      f16x8 kf1 = *(const f16x8*)&Ks[(16 * t + am) * KVS + 32 + ak];
      S[t] = __builtin_amdgcn_mfma_f32_16x16x32_f16(
          qf0, kf0, (f32x4){0.f, 0.f, 0.f, 0.f}, 0, 0, 0);
      S[t] = __builtin_amdgcn_mfma_f32_16x16x32_f16(qf1, kf1, S[t], 0, 0, 0);
    }
#pragma unroll
    for (int t = 0; t < 4; t++) {
#pragma unroll
      for (int r = 0; r < 4; r++) {
        float p = __expf(S[t][r]);
        lpart[r] += p;
        Pw[(quad * 4 + r) * PSTRIDE + 16 * t + am] = (f16)p;
      }
    }
    f16x8 pa0 = *(const f16x8*)&Pw[am * PSTRIDE + ak];
    f16x8 pa1 = *(const f16x8*)&Pw[am * PSTRIDE + 32 + ak];
#pragma unroll
    for (int dt = 0; dt < 4; dt++) {
      f16x8 vf0 = *(const f16x8*)&Vs[(16 * dt + am) * KVS + ak];
      f16x8 vf1 = *(const f16x8*)&Vs[(16 * dt + am) * KVS + 32 + ak];
      Oa[dt] = __builtin_amdgcn_mfma_f32_16x16x32_f16(pa0, vf0, Oa[dt], 0, 0, 0);
      Oa[dt] = __builtin_amdgcn_mfma_f32_16x16x32_f16(pa1, vf1, Oa[dt], 0, 0, 0);
    }
  }

#pragma unroll
  for (int o = 1; o < 16; o <<= 1)
#pragma unroll
    for (int r = 0; r < 4; r++) lpart[r] += __shfl_xor(lpart[r], o, 64);

#pragma unroll
  for (int r = 0; r < 4; r++) {
    int m = m0 + quad * 4 + r;
    float inv = 1.f / lpart[r];
    f16* orow = attn + ((size_t)(bb * TSEQ + m)) * CDIM + h * DH;
#pragma unroll
    for (int dt = 0; dt < 4; dt++)
      orow[dt * 16 + am] = (f16)(Oa[dt][r] * inv);
  }
}

// ---------------- Anderson: first iteration (K=0): z += res --------------
__global__ __launch_bounds__(256) void add_res_kernel(
    float* __restrict__ z, const float* __restrict__ r) {
  size_t i = (size_t)blockIdx.x * 256 + threadIdx.x;
  z[i] += r[i];
}

// ---------------- Anderson update, K previous residuals, per-token LS -----
template <int KA>
__global__ __launch_bounds__(256) void anderson_kernel(
    float* __restrict__ z, const float* __restrict__ rescur,
    const float* __restrict__ p0, const float* __restrict__ p1,
    const float* __restrict__ p2, const float* __restrict__ p3) {
  __shared__ float sbuf[4];
  int row = blockIdx.x, tid = threadIdx.x;
  size_t base = (size_t)row * CDIM + tid;
  float r[3];
#pragma unroll
  for (int i = 0; i < 3; i++) r[i] = rescur[base + i * 256];
  const float* ps[4] = {p0, p1, p2, p3};
  float dF[KA][3];
#pragma unroll
  for (int k = 0; k < KA; k++)
#pragma unroll
    for (int i = 0; i < 3; i++) dF[k][i] = ps[k][base + i * 256] - r[i];

  float Gm[KA][KA], bv[KA];
#pragma unroll
  for (int k = 0; k < KA; k++) {
#pragma unroll
    for (int ll = k; ll < KA; ll++) {
      float p = 0.f;
#pragma unroll
      for (int i = 0; i < 3; i++) p += dF[k][i] * dF[ll][i];
      float t = block_reduce_sum(p, sbuf);
      Gm[k][ll] = t;
      Gm[ll][k] = t;
    }
  }
#pragma unroll
  for (int k = 0; k < KA; k++) Gm[k][k] += 1e-6f;
#pragma unroll
  for (int k = 0; k < KA; k++) {
    float p = 0.f;
#pragma unroll
    for (int i = 0; i < 3; i++) p += dF[k][i] * r[i];
    bv[k] = block_reduce_sum(p, sbuf);
  }
  float alpha[KA];
#pragma unroll
  for (int p = 0; p < KA; p++) {
    float inv = 1.f / Gm[p][p];
#pragma unroll
    for (int rr = p + 1; rr < KA; rr++) {
      float f = Gm[rr][p] * inv;
#pragma unroll
      for (int c = p; c < KA; c++) Gm[rr][c] -= f * Gm[p][c];
      bv[rr] -= f * bv[p];
    }
  }
#pragma unroll
  for (int p = KA - 1; p >= 0; p--) {
    float s2 = bv[p];
#pragma unroll
    for (int c = p + 1; c < KA; c++) s2 -= Gm[p][c] * alpha[c];
    alpha[p] = s2 / Gm[p][p];
  }
#pragma unroll
  for (int i = 0; i < 3; i++) {
    float d = r[i];
#pragma unroll
    for (int k = 0; k < KA; k++) d = fmaf(-dF[k][i], alpha[k], d);
    z[base + i * 256] += d;
  }
}

extern "C" void kernel_launch(void* const* d_in, const int* in_sizes, int n_in,
                              void* d_out, int out_size, void* d_ws,
                              size_t ws_size, hipStream_t stream) {
  (void)in_sizes; (void)n_in; (void)out_size; (void)ws_size;
  const float* u = (const float*)d_in[0];
  const float* iter_emb = (const float*)d_in[1];
  const float* ln1w = (const float*)d_in[2];
  const float* ln1b = (const float*)d_in[3];
  const float* wqkv = (const float*)d_in[4];
  const float* bqkv = (const float*)d_in[5];
  const float* wo = (const float*)d_in[6];
  const float* bo = (const float*)d_in[7];
  const float* ln2w = (const float*)d_in[8];
  const float* ln2b = (const float*)d_in[9];
  const float* w1 = (const float*)d_in[10];
  const float* b1 = (const float*)d_in[11];
  const float* w2 = (const float*)d_in[12];
  const float* b2 = (const float*)d_in[13];

  const size_t S = (size_t)BT * CDIM;  // 3,145,728
  float* ws = (float*)d_ws;
  // fp32 slots:
  float* z = ws + 0 * S;
  float* zattn = ws + 1 * S;
  float* res[5] = {ws + 2 * S, ws + 3 * S, ws + 4 * S, ws + 5 * S, ws + 6 * S};
  // f16 region:
  f16* q_h = (f16*)(ws + 7 * S);   // S f16: [7.0,7.5)   [B,H,T,64]
  f16* k_h = q_h + S;              // [7.5,8.0)          [B,H,T,64]
  f16* vt_h = q_h + 2 * S;         // [8.0,8.5)          [B,H,64,T]
  f16* h_h = (f16*)(ws + 7 * S);   // 4S f16 [7.0,9.0) — aliases q/k/vt
                                   // (disjoint lifetime: mlp1..mlp2 only)
  f16* x_h = (f16*)(ws + 9 * S);   // S f16 [9.0,9.5): LN out / attn out
  f16* wqkv_h = x_h + S;
  f16* wo_h = wqkv_h + (size_t)3 * CDIM * CDIM;
  f16* w1_h = wo_h + (size_t)CDIM * CDIM;
  f16* w2_h = w1_h + (size_t)4 * CDIM * CDIM;

  cvt_f16_kernel<<<1728, 256, 0, stream>>>(wqkv, wqkv_h);
  cvt_f16_kernel<<<576, 256, 0, stream>>>(wo, wo_h);
  cvt_f16_kernel<<<2304, 256, 0, stream>>>(w1, w1_h);
  cvt_f16_kernel<<<2304, 256, 0, stream>>>(w2, w2_h);
  zero_kernel<<<S / 1024, 256, 0, stream>>>((float4*)z);

  for (int it = 0; it < 6; it++) {
    ln1_kernel<<<BT, 256, 0, stream>>>(z, u, iter_emb + it * CDIM, ln1w, ln1b,
                                       x_h);
    gemm_mfma<3><<<dim3(18, 32), 256, 0, stream>>>(
        x_h, wqkv_h, bqkv, q_h, k_h, vt_h, nullptr, BT, 3 * CDIM, CDIM);
    flash_attn8<<<dim3(BBATCH * NHEAD, TSEQ / 64), 256, 0, stream>>>(
        q_h, k_h, vt_h, x_h);
    gemm_mfma64<0><<<dim3(64, 12), 256, 0, stream>>>(
        x_h, wo_h, bo, z, nullptr, zattn, BT, CDIM, CDIM);
    ln2_kernel<<<BT, 256, 0, stream>>>(zattn, ln2w, ln2b, x_h);
    gemm_mfma<1><<<dim3(24, 32), 256, 0, stream>>>(
        x_h, w1_h, b1, nullptr, nullptr, nullptr, h_h, BT, 4 * CDIM, CDIM);
    float* rcur = res[it % 5];
    gemm_mfma64<2><<<dim3(64, 12), 256, 0, stream>>>(
        h_h, w2_h, b2, zattn, z, rcur, BT, CDIM, 4 * CDIM);

    int Kh = it < 4 ? it : 4;
    if (Kh == 0) {
      add_res_kernel<<<S / 256, 256, 0, stream>>>(z, rcur);
    } else {
      const float* p[4] = {rcur, rcur, rcur, rcur};
      for (int kx = 1; kx <= Kh; kx++) p[kx - 1] = res[(it - kx) % 5];
      switch (Kh) {
        case 1: anderson_kernel<1><<<BT, 256, 0, stream>>>(z, rcur, p[0], p[1], p[2], p[3]); break;
        case 2: anderson_kernel<2><<<BT, 256, 0, stream>>>(z, rcur, p[0], p[1], p[2], p[3]); break;
        case 3: anderson_kernel<3><<<BT, 256, 0, stream>>>(z, rcur, p[0], p[1], p[2], p[3]); break;
        default: anderson_kernel<4><<<BT, 256, 0, stream>>>(z, rcur, p[0], p[1], p[2], p[3]); break;
      }
    }
  }
  hipMemcpyAsync(d_out, z, S * sizeof(float), hipMemcpyDeviceToDevice, stream);
}